// Round 13
// baseline (374.306 us; speedup 1.0000x reference)
//
#include <hip/hip_runtime.h>
#include <hip/hip_bf16.h>

#define N_NODES 50000
#define NGRAPH 64
#define HID 128
#define NLAYERS 4
#define SCAN_NB ((N_NODES + 511) / 512)   // 98 blocks
#define HIST_NB 2500                      // ceil(640000/256)
#define WPREP_NB 320                      // ceil(5*128*128/256)

typedef __attribute__((ext_vector_type(8))) __bf16 bf16x8;
typedef __attribute__((ext_vector_type(8))) unsigned short ushort8;
typedef __attribute__((ext_vector_type(4))) float f32x4;

__device__ __forceinline__ float bf2f(unsigned short u) { return __uint_as_float(((unsigned)u) << 16); }
__device__ __forceinline__ unsigned short f2bf(float f) { return __hip_bfloat16_raw(__float2bfloat16(f)).x; }
__device__ __forceinline__ float ulo(unsigned m) { return __uint_as_float(m << 16); }
__device__ __forceinline__ float uhi(unsigned m) { return __uint_as_float(m & 0xffff0000u); }

// ---------------- init: zero histogram + graph bounds + scan-done counter ----------------
__global__ void k_init(int* __restrict__ cnt, int* __restrict__ gstart, int* __restrict__ gend,
                       int* __restrict__ done) {
  int i = blockIdx.x * blockDim.x + threadIdx.x;
  if (i < N_NODES) cnt[i] = 0;
  if (i < NGRAPH) { gstart[i] = 0; gend[i] = 0; }
  if (i == 0) *done = 0;
}

// ---------------- fused: histogram over target + graph bounds + weight prep ----------------
__global__ void k_hist(const int* __restrict__ col, int E, int* __restrict__ cnt,
                       const int* __restrict__ batch, int* __restrict__ gstart, int* __restrict__ gend,
                       const float* __restrict__ Win, const float* __restrict__ Wconv,
                       unsigned short* __restrict__ WtAll) {
  if (blockIdx.x < HIST_NB) {
    int e = blockIdx.x * blockDim.x + threadIdx.x;
    if (e < E) atomicAdd(&cnt[__builtin_nontemporal_load(&col[e])], 1);
    if (e < N_NODES) {
      int b = batch[e];
      if (e == 0 || batch[e - 1] != b) gstart[b] = e;
      if (e == N_NODES - 1 || batch[e + 1] != b) gend[b] = e + 1;
    }
  } else {
    int idx = (blockIdx.x - HIST_NB) * 256 + threadIdx.x;
    if (idx >= 5 * HID * HID) return;
    int m = idx >> 14, rem = idx & 16383;
    int k = rem >> 7, n = rem & 127;
    const float* src = (m == 0) ? Win : (Wconv + (size_t)(m - 1) * HID * HID);
    WtAll[(size_t)m * HID * HID + n * HID + k] = f2bf(src[k * HID + n]);
  }
}

// ---------------- scan phase 1 + fused phase 2 (last-block pattern) ----------------
__global__ __launch_bounds__(512) void k_scan1(const int* __restrict__ cnt, int* __restrict__ excl,
                                               int* __restrict__ bsum, int* __restrict__ offs,
                                               int* __restrict__ done) {
  __shared__ int tmp[512];
  __shared__ int islast;
  const int t = threadIdx.x;
  const int i = blockIdx.x * 512 + t;
  int v = (i < N_NODES) ? cnt[i] : 0;
  tmp[t] = v;
  __syncthreads();
#pragma unroll
  for (int off = 1; off < 512; off <<= 1) {
    int u = (t >= off) ? tmp[t - off] : 0;
    __syncthreads();
    tmp[t] += u;
    __syncthreads();
  }
  if (i < N_NODES) excl[i] = tmp[t] - v;
  if (t == 511) bsum[blockIdx.x] = tmp[511];

  // completion detection: last finished block scans the block sums (order-independent)
  __threadfence();
  if (t == 0) islast = (atomicAdd(done, 1) == SCAN_NB - 1) ? 1 : 0;
  __syncthreads();
  if (!islast) return;
  __threadfence();  // acquire: all blocks' bsum stores visible
  int bv = (t < SCAN_NB) ? bsum[t] : 0;
  if (t < 128) tmp[t] = bv;
  __syncthreads();
#pragma unroll
  for (int off = 1; off < 128; off <<= 1) {
    int u = (t >= off && t < 128) ? tmp[t - off] : 0;
    __syncthreads();
    if (t < 128) tmp[t] += u;
    __syncthreads();
  }
  if (t < SCAN_NB) bsum[t] = tmp[t] - bv;       // exclusive base per block
  if (t == 127) offs[N_NODES] = tmp[127];
}

// ---------------- scan phase 3: emit offs/cursor/dinv ----------------
__global__ __launch_bounds__(512) void k_scan3(const int* __restrict__ cnt, const int* __restrict__ excl,
                                               const int* __restrict__ bsum, int* __restrict__ offs,
                                               int* __restrict__ cursor, float* __restrict__ dinv) {
  const int i = blockIdx.x * 512 + threadIdx.x;
  if (i >= N_NODES) return;
  int o = excl[i] + bsum[blockIdx.x];
  offs[i] = o;
  cursor[i] = o;
  dinv[i] = 1.0f / sqrtf((float)(cnt[i] + 1));
}

// ---------------- scatter edges into CSR buckets (uint16 src, non-temporal) ----------------
__global__ void k_fill(const int* __restrict__ row, const int* __restrict__ col, int E,
                       int* __restrict__ cursor, unsigned short* __restrict__ csr_src) {
  int e = blockIdx.x * blockDim.x + threadIdx.x;
  if (e >= E) return;
  int c = __builtin_nontemporal_load(&col[e]);
  int r = __builtin_nontemporal_load(&row[e]);
  int pos = atomicAdd(&cursor[c], 1);
  __builtin_nontemporal_store((unsigned short)r, &csr_src[pos]);
}

// ---------------- MFMA GEMM: Y[M,128] = A @ W; LDS epilogue, row-major bf16 out ----------------
// SCALE: multiply output row r by dinv[r] (g = dinv*hW).
template <bool AF32, bool BIAS, bool RELU, bool SCALE>
__global__ __launch_bounds__(256) void k_gemm_mfma(const void* __restrict__ Av,
                                                   const unsigned short* __restrict__ Wt,
                                                   const float* __restrict__ bias,
                                                   const float* __restrict__ dinv,
                                                   unsigned short* __restrict__ Y, int M) {
  __shared__ float ys[64][132];
  const int wave = threadIdx.x >> 6;
  const int lane = threadIdx.x & 63;
  const int row16 = (blockIdx.x * 4 + wave) * 16;
  const int lr = lane & 15;
  const int lk = (lane >> 4) * 8;

  f32x4 acc[8];
#pragma unroll
  for (int i = 0; i < 8; ++i) acc[i] = (f32x4){0.f, 0.f, 0.f, 0.f};

  const int arow = min(row16 + lr, M - 1);   // clamp; stores guarded
#pragma unroll
  for (int ks = 0; ks < 4; ++ks) {
    const int k0 = ks * 32 + lk;
    bf16x8 a;
    if (AF32) {
      const float* Af = (const float*)Av;
      float4 f0 = *(const float4*)(Af + (size_t)arow * HID + k0);
      float4 f1 = *(const float4*)(Af + (size_t)arow * HID + k0 + 4);
      ushort8 u;
      u[0] = f2bf(f0.x); u[1] = f2bf(f0.y); u[2] = f2bf(f0.z); u[3] = f2bf(f0.w);
      u[4] = f2bf(f1.x); u[5] = f2bf(f1.y); u[6] = f2bf(f1.z); u[7] = f2bf(f1.w);
      a = __builtin_bit_cast(bf16x8, u);
    } else {
      const unsigned short* Ab = (const unsigned short*)Av;
      a = *(const bf16x8*)(Ab + (size_t)arow * HID + k0);
    }
#pragma unroll
    for (int nt = 0; nt < 8; ++nt) {
      bf16x8 b = *(const bf16x8*)(Wt + (size_t)(nt * 16 + lr) * HID + k0);
      acc[nt] = __builtin_amdgcn_mfma_f32_16x16x32_bf16(a, b, acc[nt], 0, 0, 0);
    }
  }

  // acc -> LDS.  D layout: col = lane&15, row = (lane>>4)*4 + r
  const int wrow = wave * 16 + (lane >> 4) * 4;
#pragma unroll
  for (int nt = 0; nt < 8; ++nt) {
    const int c = nt * 16 + lr;
#pragma unroll
    for (int r = 0; r < 4; ++r) ys[wrow + r][c] = acc[nt][r];
  }
  __syncthreads();

  // epilogue: thread t -> row t>>2, full 32-col strip q = t&3 (4x ushort8 = 64B coalesced)
  const int er = threadIdx.x >> 2;
  const int q = threadIdx.x & 3;
  const int grow = blockIdx.x * 64 + er;
  if (grow < M) {
    float scale = SCALE ? dinv[grow] : 1.f;
    ushort8 pk[4];
#pragma unroll
    for (int h = 0; h < 4; ++h) {
#pragma unroll
      for (int j = 0; j < 8; ++j) {
        int c = q * 32 + h * 8 + j;
        float v = ys[er][c];
        if (BIAS) v += bias[c];
        if (RELU) v = fmaxf(v, 0.f);
        if (SCALE) v *= scale;
        pk[h][j] = f2bf(v);
      }
    }
    unsigned short* dst = Y + (size_t)grow * HID + q * 32;
    *(ushort8*)(dst)      = pk[0];
    *(ushort8*)(dst + 8)  = pk[1];
    *(ushort8*)(dst + 16) = pk[2];
    *(ushort8*)(dst + 24) = pk[3];
  }
}

// ---------------- aggregation: wave/node, 4 edge-slots x 16 lanes x uint4 (16B) ----------------
__global__ __launch_bounds__(256) void k_agg(const unsigned short* __restrict__ g, const int* __restrict__ offs,
                                             const unsigned short* __restrict__ csr_src,
                                             const float* __restrict__ dinv,
                                             const float* __restrict__ bias, unsigned short* __restrict__ out) {
  const int wave = threadIdx.x >> 6;
  const int lane = threadIdx.x & 63;
  const int v = blockIdx.x * 4 + wave;
  if (v >= N_NODES) return;
  const int s = lane >> 4;          // edge slot 0..3
  const int c = lane & 15;          // 16B chunk within 256B row

  const uint4* g4 = (const uint4*)g;   // row = 16 x uint4

  float a0 = 0.f, a1 = 0.f, a2 = 0.f, a3 = 0.f, a4 = 0.f, a5 = 0.f, a6 = 0.f, a7 = 0.f;
  if (s == 0) {                        // self term in slot 0
    uint4 m = g4[(size_t)v * 16 + c];
    a0 = ulo(m.x); a1 = uhi(m.x); a2 = ulo(m.y); a3 = uhi(m.y);
    a4 = ulo(m.z); a5 = uhi(m.z); a6 = ulo(m.w); a7 = uhi(m.w);
  }

  const int lo = offs[v], hi = offs[v + 1];
  int idx = lo + s;
  for (; idx + 4 < hi; idx += 8) {
    int s0 = csr_src[idx];
    int s1 = csr_src[idx + 4];
    uint4 m0 = g4[(size_t)s0 * 16 + c];
    uint4 m1 = g4[(size_t)s1 * 16 + c];
    a0 += ulo(m0.x) + ulo(m1.x); a1 += uhi(m0.x) + uhi(m1.x);
    a2 += ulo(m0.y) + ulo(m1.y); a3 += uhi(m0.y) + uhi(m1.y);
    a4 += ulo(m0.z) + ulo(m1.z); a5 += uhi(m0.z) + uhi(m1.z);
    a6 += ulo(m0.w) + ulo(m1.w); a7 += uhi(m0.w) + uhi(m1.w);
  }
  if (idx < hi) {
    uint4 m0 = g4[(size_t)csr_src[idx] * 16 + c];
    a0 += ulo(m0.x); a1 += uhi(m0.x);
    a2 += ulo(m0.y); a3 += uhi(m0.y);
    a4 += ulo(m0.z); a5 += uhi(m0.z);
    a6 += ulo(m0.w); a7 += uhi(m0.w);
  }

  a0 += __shfl_xor(a0, 16, 64); a0 += __shfl_xor(a0, 32, 64);
  a1 += __shfl_xor(a1, 16, 64); a1 += __shfl_xor(a1, 32, 64);
  a2 += __shfl_xor(a2, 16, 64); a2 += __shfl_xor(a2, 32, 64);
  a3 += __shfl_xor(a3, 16, 64); a3 += __shfl_xor(a3, 32, 64);
  a4 += __shfl_xor(a4, 16, 64); a4 += __shfl_xor(a4, 32, 64);
  a5 += __shfl_xor(a5, 16, 64); a5 += __shfl_xor(a5, 32, 64);
  a6 += __shfl_xor(a6, 16, 64); a6 += __shfl_xor(a6, 32, 64);
  a7 += __shfl_xor(a7, 16, 64); a7 += __shfl_xor(a7, 32, 64);

  if (s == 0) {
    const float d = dinv[v];
    float4 b0 = ((const float4*)bias)[c * 2];
    float4 b1 = ((const float4*)bias)[c * 2 + 1];
    float o0 = fmaxf(d * a0 + b0.x, 0.f), o1 = fmaxf(d * a1 + b0.y, 0.f);
    float o2 = fmaxf(d * a2 + b0.z, 0.f), o3 = fmaxf(d * a3 + b0.w, 0.f);
    float o4 = fmaxf(d * a4 + b1.x, 0.f), o5 = fmaxf(d * a5 + b1.y, 0.f);
    float o6 = fmaxf(d * a6 + b1.z, 0.f), o7 = fmaxf(d * a7 + b1.w, 0.f);
    uint4 pk;
    pk.x = (unsigned)f2bf(o0) | ((unsigned)f2bf(o1) << 16);
    pk.y = (unsigned)f2bf(o2) | ((unsigned)f2bf(o3) << 16);
    pk.z = (unsigned)f2bf(o4) | ((unsigned)f2bf(o5) << 16);
    pk.w = (unsigned)f2bf(o6) | ((unsigned)f2bf(o7) << 16);
    ((uint4*)out)[(size_t)v * 16 + c] = pk;
  }
}

// ---------------- fused mean pool + heads ----------------
__global__ __launch_bounds__(1024) void k_poolheads(const unsigned short* __restrict__ h,
                                                    const int* __restrict__ gstart, const int* __restrict__ gend,
                                                    const float* __restrict__ W0, const float* __restrict__ b0,
                                                    const float* __restrict__ W1, const float* __restrict__ b1,
                                                    const float* __restrict__ W2, const float* __restrict__ b2,
                                                    float* __restrict__ out) {
  __shared__ float red[1024];
  __shared__ float pm[HID];
  const int g = blockIdx.x;
  const int tid = threadIdx.x;
  const int j = tid & 127;
  const int r0 = tid >> 7;
  const int lo = gstart[g], hi = gend[g];
  float acc = 0.f;
  for (int v = lo + r0; v < hi; v += 8) acc += bf2f(h[(size_t)v * HID + j]);
  red[tid] = acc;
  __syncthreads();
  if (r0 < 4) red[tid] += red[tid + 512];
  __syncthreads();
  if (r0 < 2) red[tid] += red[tid + 256];
  __syncthreads();
  if (r0 < 1) {
    float s = red[tid] + red[tid + 128];
    pm[j] = s / fmaxf((float)(hi - lo), 1.f);
  }
  __syncthreads();
  if (tid < 384) {
    const int t = tid >> 7;        // head 0..2
    const int cc = tid & 127;      // col
    const float* W = (t == 0) ? W0 : ((t == 1) ? W1 : W2);
    const float* b = (t == 0) ? b0 : ((t == 1) ? b1 : b2);
    float a2 = 0.f;
#pragma unroll 8
    for (int k = 0; k < HID; ++k) a2 += pm[k] * W[k * HID + cc];
    out[((size_t)t * NGRAPH + g) * HID + cc] = a2 + b[cc];
  }
}

extern "C" void kernel_launch(void* const* d_in, const int* in_sizes, int n_in,
                              void* d_out, int out_size, void* d_ws, size_t ws_size,
                              hipStream_t stream) {
  const float* x     = (const float*)d_in[0];
  const int*   ei    = (const int*)d_in[1];
  const int*   batch = (const int*)d_in[2];
  const float* W_in  = (const float*)d_in[3];
  const float* b_in  = (const float*)d_in[4];
  const float* convW = (const float*)d_in[5];
  const float* convb = (const float*)d_in[6];
  const float* W_def = (const float*)d_in[7];
  const float* b_def = (const float*)d_in[8];
  const float* W_syn = (const float*)d_in[9];
  const float* b_syn = (const float*)d_in[10];
  const float* W_rel = (const float*)d_in[11];
  const float* b_rel = (const float*)d_in[12];

  const int E = in_sizes[1] / 2;  // 640000
  const int* row = ei;            // source
  const int* col = ei + E;        // target

  char* base = (char*)d_ws;
  size_t off = 0;
  auto alloc = [&](size_t bytes) -> void* {
    void* p = base + off;
    off += (bytes + 255) & ~size_t(255);
    return p;
  };
  int*   cnt     = (int*)  alloc((size_t)N_NODES * 4);
  float* dinv    = (float*)alloc((size_t)N_NODES * 4);
  int*   offs    = (int*)  alloc((size_t)(N_NODES + 1) * 4);
  int*   cursor  = (int*)  alloc((size_t)N_NODES * 4);
  int*   excl    = (int*)  alloc((size_t)N_NODES * 4);
  int*   bsum    = (int*)  alloc((size_t)SCAN_NB * 4);
  int*   done    = (int*)  alloc(256);
  unsigned short* csr_src = (unsigned short*)alloc((size_t)E * 2);
  unsigned short* hA = (unsigned short*)alloc((size_t)N_NODES * HID * 2);  // bf16 h
  unsigned short* hB = (unsigned short*)alloc((size_t)N_NODES * HID * 2);  // bf16 g = dinv*hW
  unsigned short* WtAll = (unsigned short*)alloc((size_t)5 * HID * HID * 2);
  int*   gstart  = (int*)  alloc((size_t)NGRAPH * 4);
  int*   gend    = (int*)  alloc((size_t)NGRAPH * 4);

  // graph preprocessing
  k_init<<<(N_NODES + 255) / 256, 256, 0, stream>>>(cnt, gstart, gend, done);
  k_hist<<<HIST_NB + WPREP_NB, 256, 0, stream>>>(col, E, cnt, batch, gstart, gend, W_in, convW, WtAll);
  k_scan1<<<SCAN_NB, 512, 0, stream>>>(cnt, excl, bsum, offs, done);
  k_scan3<<<SCAN_NB, 512, 0, stream>>>(cnt, excl, bsum, offs, cursor, dinv);
  k_fill<<<(E + 255) / 256, 256, 0, stream>>>(row, col, E, cursor, csr_src);

  const int gemm_grid = (N_NODES + 63) / 64;
  // h = relu(x @ W_in + b_in)
  k_gemm_mfma<true, true, true, false><<<gemm_grid, 256, 0, stream>>>(x, WtAll, b_in, nullptr, hA, N_NODES);

  for (int i = 0; i < NLAYERS; ++i) {
    // g = dinv * (h @ W_i)
    k_gemm_mfma<false, false, false, true><<<gemm_grid, 256, 0, stream>>>(
        hA, WtAll + (size_t)(i + 1) * HID * HID, nullptr, dinv, hB, N_NODES);
    k_agg<<<(N_NODES + 3) / 4, 256, 0, stream>>>(hB, offs, csr_src, dinv, convb + (size_t)i * HID, hA);
  }

  k_poolheads<<<NGRAPH, 1024, 0, stream>>>(hA, gstart, gend, W_def, b_def, W_syn, b_syn, W_rel, b_rel,
                                           (float*)d_out);
}

// Round 15
// 346.843 us; speedup vs baseline: 1.0792x; 1.0792x over previous
//
#include <hip/hip_runtime.h>
#include <hip/hip_bf16.h>

#define N_NODES 50000
#define NGRAPH 64
#define HID 128
#define NLAYERS 4
#define SCAN_NB ((N_NODES + 511) / 512)   // 98 blocks
#define HIST_NB 2500                      // ceil(640000/256)
#define WPREP_NB 320                      // ceil(5*128*128/256)

typedef __attribute__((ext_vector_type(8))) __bf16 bf16x8;
typedef __attribute__((ext_vector_type(8))) unsigned short ushort8;
typedef __attribute__((ext_vector_type(4))) float f32x4;

__device__ __forceinline__ float bf2f(unsigned short u) { return __uint_as_float(((unsigned)u) << 16); }
__device__ __forceinline__ unsigned short f2bf(float f) { return __hip_bfloat16_raw(__float2bfloat16(f)).x; }
__device__ __forceinline__ float ulo(unsigned m) { return __uint_as_float(m << 16); }
__device__ __forceinline__ float uhi(unsigned m) { return __uint_as_float(m & 0xffff0000u); }

// ---------------- init: zero histogram + graph bounds ----------------
__global__ void k_init(int* __restrict__ cnt, int* __restrict__ gstart, int* __restrict__ gend) {
  int i = blockIdx.x * blockDim.x + threadIdx.x;
  if (i < N_NODES) cnt[i] = 0;
  if (i < NGRAPH) { gstart[i] = 0; gend[i] = 0; }
}

// ---------------- fused: histogram over target + graph bounds + weight prep ----------------
__global__ void k_hist(const int* __restrict__ col, int E, int* __restrict__ cnt,
                       const int* __restrict__ batch, int* __restrict__ gstart, int* __restrict__ gend,
                       const float* __restrict__ Win, const float* __restrict__ Wconv,
                       unsigned short* __restrict__ WtAll) {
  if (blockIdx.x < HIST_NB) {
    int e = blockIdx.x * blockDim.x + threadIdx.x;
    if (e < E) atomicAdd(&cnt[col[e]], 1);
    if (e < N_NODES) {
      int b = batch[e];
      if (e == 0 || batch[e - 1] != b) gstart[b] = e;
      if (e == N_NODES - 1 || batch[e + 1] != b) gend[b] = e + 1;
    }
  } else {
    int idx = (blockIdx.x - HIST_NB) * 256 + threadIdx.x;
    if (idx >= 5 * HID * HID) return;
    int m = idx >> 14, rem = idx & 16383;
    int k = rem >> 7, n = rem & 127;
    const float* src = (m == 0) ? Win : (Wconv + (size_t)(m - 1) * HID * HID);
    WtAll[(size_t)m * HID * HID + n * HID + k] = f2bf(src[k * HID + n]);
  }
}

// ---------------- multi-block scan ----------------
__global__ __launch_bounds__(512) void k_scan1(const int* __restrict__ cnt, int* __restrict__ excl,
                                               int* __restrict__ bsum) {
  __shared__ int tmp[512];
  const int t = threadIdx.x;
  const int i = blockIdx.x * 512 + t;
  int v = (i < N_NODES) ? cnt[i] : 0;
  tmp[t] = v;
  __syncthreads();
#pragma unroll
  for (int off = 1; off < 512; off <<= 1) {
    int u = (t >= off) ? tmp[t - off] : 0;
    __syncthreads();
    tmp[t] += u;
    __syncthreads();
  }
  if (i < N_NODES) excl[i] = tmp[t] - v;
  if (t == 511) bsum[blockIdx.x] = tmp[511];
}

__global__ __launch_bounds__(128) void k_scan2(int* __restrict__ bsum, int* __restrict__ offs) {
  __shared__ int tmp[128];
  const int t = threadIdx.x;
  int v = (t < SCAN_NB) ? bsum[t] : 0;
  tmp[t] = v;
  __syncthreads();
#pragma unroll
  for (int off = 1; off < 128; off <<= 1) {
    int u = (t >= off) ? tmp[t - off] : 0;
    __syncthreads();
    tmp[t] += u;
    __syncthreads();
  }
  if (t < SCAN_NB) bsum[t] = tmp[t] - v;
  if (t == 127) offs[N_NODES] = tmp[127];
}

__global__ __launch_bounds__(512) void k_scan3(const int* __restrict__ cnt, const int* __restrict__ excl,
                                               const int* __restrict__ bsum, int* __restrict__ offs,
                                               int* __restrict__ cursor, float* __restrict__ dinv) {
  const int i = blockIdx.x * 512 + threadIdx.x;
  if (i >= N_NODES) return;
  int o = excl[i] + bsum[blockIdx.x];
  offs[i] = o;
  cursor[i] = o;
  dinv[i] = 1.0f / sqrtf((float)(cnt[i] + 1));
}

// ---------------- scatter edges into CSR buckets (uint16 src) ----------------
__global__ void k_fill(const int* __restrict__ row, const int* __restrict__ col, int E,
                       int* __restrict__ cursor, unsigned short* __restrict__ csr_src) {
  int e = blockIdx.x * blockDim.x + threadIdx.x;
  if (e >= E) return;
  int pos = atomicAdd(&cursor[col[e]], 1);
  csr_src[pos] = (unsigned short)row[e];
}

// ---------------- MFMA GEMM: Y[M,128] = A @ W; LDS epilogue, row-major bf16 out ----------------
// SCALE: multiply output row r by dinv[r] (g = dinv*hW).
template <bool AF32, bool BIAS, bool RELU, bool SCALE>
__global__ __launch_bounds__(256) void k_gemm_mfma(const void* __restrict__ Av,
                                                   const unsigned short* __restrict__ Wt,
                                                   const float* __restrict__ bias,
                                                   const float* __restrict__ dinv,
                                                   unsigned short* __restrict__ Y, int M) {
  __shared__ float ys[64][132];
  const int wave = threadIdx.x >> 6;
  const int lane = threadIdx.x & 63;
  const int row16 = (blockIdx.x * 4 + wave) * 16;
  const int lr = lane & 15;
  const int lk = (lane >> 4) * 8;

  f32x4 acc[8];
#pragma unroll
  for (int i = 0; i < 8; ++i) acc[i] = (f32x4){0.f, 0.f, 0.f, 0.f};

  const int arow = min(row16 + lr, M - 1);   // clamp; stores guarded
#pragma unroll
  for (int ks = 0; ks < 4; ++ks) {
    const int k0 = ks * 32 + lk;
    bf16x8 a;
    if (AF32) {
      const float* Af = (const float*)Av;
      float4 f0 = *(const float4*)(Af + (size_t)arow * HID + k0);
      float4 f1 = *(const float4*)(Af + (size_t)arow * HID + k0 + 4);
      ushort8 u;
      u[0] = f2bf(f0.x); u[1] = f2bf(f0.y); u[2] = f2bf(f0.z); u[3] = f2bf(f0.w);
      u[4] = f2bf(f1.x); u[5] = f2bf(f1.y); u[6] = f2bf(f1.z); u[7] = f2bf(f1.w);
      a = __builtin_bit_cast(bf16x8, u);
    } else {
      const unsigned short* Ab = (const unsigned short*)Av;
      a = *(const bf16x8*)(Ab + (size_t)arow * HID + k0);
    }
#pragma unroll
    for (int nt = 0; nt < 8; ++nt) {
      bf16x8 b = *(const bf16x8*)(Wt + (size_t)(nt * 16 + lr) * HID + k0);
      acc[nt] = __builtin_amdgcn_mfma_f32_16x16x32_bf16(a, b, acc[nt], 0, 0, 0);
    }
  }

  // acc -> LDS.  D layout: col = lane&15, row = (lane>>4)*4 + r
  const int wrow = wave * 16 + (lane >> 4) * 4;
#pragma unroll
  for (int nt = 0; nt < 8; ++nt) {
    const int c = nt * 16 + lr;
#pragma unroll
    for (int r = 0; r < 4; ++r) ys[wrow + r][c] = acc[nt][r];
  }
  __syncthreads();

  // epilogue: thread t -> row t>>2, full 32-col strip q = t&3 (4x ushort8 = 64B coalesced)
  const int er = threadIdx.x >> 2;
  const int q = threadIdx.x & 3;
  const int grow = blockIdx.x * 64 + er;
  if (grow < M) {
    float scale = SCALE ? dinv[grow] : 1.f;
    ushort8 pk[4];
#pragma unroll
    for (int h = 0; h < 4; ++h) {
#pragma unroll
      for (int j = 0; j < 8; ++j) {
        int c = q * 32 + h * 8 + j;
        float v = ys[er][c];
        if (BIAS) v += bias[c];
        if (RELU) v = fmaxf(v, 0.f);
        if (SCALE) v *= scale;
        pk[h][j] = f2bf(v);
      }
    }
    unsigned short* dst = Y + (size_t)grow * HID + q * 32;
    *(ushort8*)(dst)      = pk[0];
    *(ushort8*)(dst + 8)  = pk[1];
    *(ushort8*)(dst + 16) = pk[2];
    *(ushort8*)(dst + 24) = pk[3];
  }
}

// ---------------- aggregation: wave/node, 4 edge-slots x 16 lanes x uint4 (16B) ----------------
__global__ __launch_bounds__(256) void k_agg(const unsigned short* __restrict__ g, const int* __restrict__ offs,
                                             const unsigned short* __restrict__ csr_src,
                                             const float* __restrict__ dinv,
                                             const float* __restrict__ bias, unsigned short* __restrict__ out) {
  const int wave = threadIdx.x >> 6;
  const int lane = threadIdx.x & 63;
  const int v = blockIdx.x * 4 + wave;
  if (v >= N_NODES) return;
  const int s = lane >> 4;          // edge slot 0..3
  const int c = lane & 15;          // 16B chunk within 256B row

  const uint4* g4 = (const uint4*)g;   // row = 16 x uint4

  float a0 = 0.f, a1 = 0.f, a2 = 0.f, a3 = 0.f, a4 = 0.f, a5 = 0.f, a6 = 0.f, a7 = 0.f;
  if (s == 0) {                        // self term in slot 0
    uint4 m = g4[(size_t)v * 16 + c];
    a0 = ulo(m.x); a1 = uhi(m.x); a2 = ulo(m.y); a3 = uhi(m.y);
    a4 = ulo(m.z); a5 = uhi(m.z); a6 = ulo(m.w); a7 = uhi(m.w);
  }

  const int lo = offs[v], hi = offs[v + 1];
  int idx = lo + s;
  for (; idx + 4 < hi; idx += 8) {
    int s0 = csr_src[idx];
    int s1 = csr_src[idx + 4];
    uint4 m0 = g4[(size_t)s0 * 16 + c];
    uint4 m1 = g4[(size_t)s1 * 16 + c];
    a0 += ulo(m0.x) + ulo(m1.x); a1 += uhi(m0.x) + uhi(m1.x);
    a2 += ulo(m0.y) + ulo(m1.y); a3 += uhi(m0.y) + uhi(m1.y);
    a4 += ulo(m0.z) + ulo(m1.z); a5 += uhi(m0.z) + uhi(m1.z);
    a6 += ulo(m0.w) + ulo(m1.w); a7 += uhi(m0.w) + uhi(m1.w);
  }
  if (idx < hi) {
    uint4 m0 = g4[(size_t)csr_src[idx] * 16 + c];
    a0 += ulo(m0.x); a1 += uhi(m0.x);
    a2 += ulo(m0.y); a3 += uhi(m0.y);
    a4 += ulo(m0.z); a5 += uhi(m0.z);
    a6 += ulo(m0.w); a7 += uhi(m0.w);
  }

  a0 += __shfl_xor(a0, 16, 64); a0 += __shfl_xor(a0, 32, 64);
  a1 += __shfl_xor(a1, 16, 64); a1 += __shfl_xor(a1, 32, 64);
  a2 += __shfl_xor(a2, 16, 64); a2 += __shfl_xor(a2, 32, 64);
  a3 += __shfl_xor(a3, 16, 64); a3 += __shfl_xor(a3, 32, 64);
  a4 += __shfl_xor(a4, 16, 64); a4 += __shfl_xor(a4, 32, 64);
  a5 += __shfl_xor(a5, 16, 64); a5 += __shfl_xor(a5, 32, 64);
  a6 += __shfl_xor(a6, 16, 64); a6 += __shfl_xor(a6, 32, 64);
  a7 += __shfl_xor(a7, 16, 64); a7 += __shfl_xor(a7, 32, 64);

  if (s == 0) {
    const float d = dinv[v];
    float4 b0 = ((const float4*)bias)[c * 2];
    float4 b1 = ((const float4*)bias)[c * 2 + 1];
    float o0 = fmaxf(d * a0 + b0.x, 0.f), o1 = fmaxf(d * a1 + b0.y, 0.f);
    float o2 = fmaxf(d * a2 + b0.z, 0.f), o3 = fmaxf(d * a3 + b0.w, 0.f);
    float o4 = fmaxf(d * a4 + b1.x, 0.f), o5 = fmaxf(d * a5 + b1.y, 0.f);
    float o6 = fmaxf(d * a6 + b1.z, 0.f), o7 = fmaxf(d * a7 + b1.w, 0.f);
    uint4 pk;
    pk.x = (unsigned)f2bf(o0) | ((unsigned)f2bf(o1) << 16);
    pk.y = (unsigned)f2bf(o2) | ((unsigned)f2bf(o3) << 16);
    pk.z = (unsigned)f2bf(o4) | ((unsigned)f2bf(o5) << 16);
    pk.w = (unsigned)f2bf(o6) | ((unsigned)f2bf(o7) << 16);
    ((uint4*)out)[(size_t)v * 16 + c] = pk;
  }
}

// ---------------- fused mean pool + heads ----------------
__global__ __launch_bounds__(1024) void k_poolheads(const unsigned short* __restrict__ h,
                                                    const int* __restrict__ gstart, const int* __restrict__ gend,
                                                    const float* __restrict__ W0, const float* __restrict__ b0,
                                                    const float* __restrict__ W1, const float* __restrict__ b1,
                                                    const float* __restrict__ W2, const float* __restrict__ b2,
                                                    float* __restrict__ out) {
  __shared__ float red[1024];
  __shared__ float pm[HID];
  const int g = blockIdx.x;
  const int tid = threadIdx.x;
  const int j = tid & 127;
  const int r0 = tid >> 7;
  const int lo = gstart[g], hi = gend[g];
  float acc = 0.f;
  for (int v = lo + r0; v < hi; v += 8) acc += bf2f(h[(size_t)v * HID + j]);
  red[tid] = acc;
  __syncthreads();
  if (r0 < 4) red[tid] += red[tid + 512];
  __syncthreads();
  if (r0 < 2) red[tid] += red[tid + 256];
  __syncthreads();
  if (r0 < 1) {
    float s = red[tid] + red[tid + 128];
    pm[j] = s / fmaxf((float)(hi - lo), 1.f);
  }
  __syncthreads();
  if (tid < 384) {
    const int t = tid >> 7;        // head 0..2
    const int cc = tid & 127;      // col
    const float* W = (t == 0) ? W0 : ((t == 1) ? W1 : W2);
    const float* b = (t == 0) ? b0 : ((t == 1) ? b1 : b2);
    float a2 = 0.f;
#pragma unroll 8
    for (int k = 0; k < HID; ++k) a2 += pm[k] * W[k * HID + cc];
    out[((size_t)t * NGRAPH + g) * HID + cc] = a2 + b[cc];
  }
}

extern "C" void kernel_launch(void* const* d_in, const int* in_sizes, int n_in,
                              void* d_out, int out_size, void* d_ws, size_t ws_size,
                              hipStream_t stream) {
  const float* x     = (const float*)d_in[0];
  const int*   ei    = (const int*)d_in[1];
  const int*   batch = (const int*)d_in[2];
  const float* W_in  = (const float*)d_in[3];
  const float* b_in  = (const float*)d_in[4];
  const float* convW = (const float*)d_in[5];
  const float* convb = (const float*)d_in[6];
  const float* W_def = (const float*)d_in[7];
  const float* b_def = (const float*)d_in[8];
  const float* W_syn = (const float*)d_in[9];
  const float* b_syn = (const float*)d_in[10];
  const float* W_rel = (const float*)d_in[11];
  const float* b_rel = (const float*)d_in[12];

  const int E = in_sizes[1] / 2;  // 640000
  const int* row = ei;            // source
  const int* col = ei + E;        // target

  char* base = (char*)d_ws;
  size_t off = 0;
  auto alloc = [&](size_t bytes) -> void* {
    void* p = base + off;
    off += (bytes + 255) & ~size_t(255);
    return p;
  };
  int*   cnt     = (int*)  alloc((size_t)N_NODES * 4);
  float* dinv    = (float*)alloc((size_t)N_NODES * 4);
  int*   offs    = (int*)  alloc((size_t)(N_NODES + 1) * 4);
  int*   cursor  = (int*)  alloc((size_t)N_NODES * 4);
  int*   excl    = (int*)  alloc((size_t)N_NODES * 4);
  int*   bsum    = (int*)  alloc((size_t)SCAN_NB * 4);
  unsigned short* csr_src = (unsigned short*)alloc((size_t)E * 2);
  unsigned short* hA = (unsigned short*)alloc((size_t)N_NODES * HID * 2);  // bf16 h
  unsigned short* hB = (unsigned short*)alloc((size_t)N_NODES * HID * 2);  // bf16 g = dinv*hW
  unsigned short* WtAll = (unsigned short*)alloc((size_t)5 * HID * HID * 2);
  int*   gstart  = (int*)  alloc((size_t)NGRAPH * 4);
  int*   gend    = (int*)  alloc((size_t)NGRAPH * 4);

  // graph preprocessing
  k_init<<<(N_NODES + 255) / 256, 256, 0, stream>>>(cnt, gstart, gend);
  k_hist<<<HIST_NB + WPREP_NB, 256, 0, stream>>>(col, E, cnt, batch, gstart, gend, W_in, convW, WtAll);
  k_scan1<<<SCAN_NB, 512, 0, stream>>>(cnt, excl, bsum);
  k_scan2<<<1, 128, 0, stream>>>(bsum, offs);
  k_scan3<<<SCAN_NB, 512, 0, stream>>>(cnt, excl, bsum, offs, cursor, dinv);
  k_fill<<<(E + 255) / 256, 256, 0, stream>>>(row, col, E, cursor, csr_src);

  const int gemm_grid = (N_NODES + 63) / 64;
  // h = relu(x @ W_in + b_in)
  k_gemm_mfma<true, true, true, false><<<gemm_grid, 256, 0, stream>>>(x, WtAll, b_in, nullptr, hA, N_NODES);

  for (int i = 0; i < NLAYERS; ++i) {
    // g = dinv * (h @ W_i)
    k_gemm_mfma<false, false, false, true><<<gemm_grid, 256, 0, stream>>>(
        hA, WtAll + (size_t)(i + 1) * HID * HID, nullptr, dinv, hB, N_NODES);
    k_agg<<<(N_NODES + 3) / 4, 256, 0, stream>>>(hB, offs, csr_src, dinv, convb + (size_t)i * HID, hA);
  }

  k_poolheads<<<NGRAPH, 1024, 0, stream>>>(hA, gstart, gend, W_def, b_def, W_syn, b_syn, W_rel, b_rel,
                                           (float*)d_out);
}

// Round 16
// 326.076 us; speedup vs baseline: 1.1479x; 1.0637x over previous
//
#include <hip/hip_runtime.h>
#include <hip/hip_bf16.h>

#define N_NODES 50000
#define NGRAPH 64
#define HID 128
#define NLAYERS 4
#define SCAN_NB ((N_NODES + 511) / 512)   // 98 blocks
#define HIST_NB 2500                      // ceil(640000/256)
#define WPREP_NB 320                      // ceil(5*128*128/256)

typedef __attribute__((ext_vector_type(8))) __bf16 bf16x8;
typedef __attribute__((ext_vector_type(8))) unsigned short ushort8;
typedef __attribute__((ext_vector_type(4))) float f32x4;

__device__ __forceinline__ float bf2f(unsigned short u) { return __uint_as_float(((unsigned)u) << 16); }
__device__ __forceinline__ unsigned short f2bf(float f) { return __hip_bfloat16_raw(__float2bfloat16(f)).x; }
__device__ __forceinline__ float ulo(unsigned m) { return __uint_as_float(m << 16); }
__device__ __forceinline__ float uhi(unsigned m) { return __uint_as_float(m & 0xffff0000u); }

// ---------------- init: zero histogram + graph bounds ----------------
__global__ void k_init(int* __restrict__ cnt, int* __restrict__ gstart, int* __restrict__ gend) {
  int i = blockIdx.x * blockDim.x + threadIdx.x;
  if (i < N_NODES) cnt[i] = 0;
  if (i < NGRAPH) { gstart[i] = 0; gend[i] = 0; }
}

// ---------------- fused: histogram over target + graph bounds + weight prep ----------------
__global__ void k_hist(const int* __restrict__ col, int E, int* __restrict__ cnt,
                       const int* __restrict__ batch, int* __restrict__ gstart, int* __restrict__ gend,
                       const float* __restrict__ Win, const float* __restrict__ Wconv,
                       unsigned short* __restrict__ WtAll) {
  if (blockIdx.x < HIST_NB) {
    int e = blockIdx.x * blockDim.x + threadIdx.x;
    if (e < E) atomicAdd(&cnt[col[e]], 1);
    if (e < N_NODES) {
      int b = batch[e];
      if (e == 0 || batch[e - 1] != b) gstart[b] = e;
      if (e == N_NODES - 1 || batch[e + 1] != b) gend[b] = e + 1;
    }
  } else {
    int idx = (blockIdx.x - HIST_NB) * 256 + threadIdx.x;
    if (idx >= 5 * HID * HID) return;
    int m = idx >> 14, rem = idx & 16383;
    int k = rem >> 7, n = rem & 127;
    const float* src = (m == 0) ? Win : (Wconv + (size_t)(m - 1) * HID * HID);
    WtAll[(size_t)m * HID * HID + n * HID + k] = f2bf(src[k * HID + n]);
  }
}

// ---------------- multi-block scan ----------------
__global__ __launch_bounds__(512) void k_scan1(const int* __restrict__ cnt, int* __restrict__ excl,
                                               int* __restrict__ bsum) {
  __shared__ int tmp[512];
  const int t = threadIdx.x;
  const int i = blockIdx.x * 512 + t;
  int v = (i < N_NODES) ? cnt[i] : 0;
  tmp[t] = v;
  __syncthreads();
#pragma unroll
  for (int off = 1; off < 512; off <<= 1) {
    int u = (t >= off) ? tmp[t - off] : 0;
    __syncthreads();
    tmp[t] += u;
    __syncthreads();
  }
  if (i < N_NODES) excl[i] = tmp[t] - v;
  if (t == 511) bsum[blockIdx.x] = tmp[511];
}

__global__ __launch_bounds__(128) void k_scan2(int* __restrict__ bsum, int* __restrict__ offs) {
  __shared__ int tmp[128];
  const int t = threadIdx.x;
  int v = (t < SCAN_NB) ? bsum[t] : 0;
  tmp[t] = v;
  __syncthreads();
#pragma unroll
  for (int off = 1; off < 128; off <<= 1) {
    int u = (t >= off) ? tmp[t - off] : 0;
    __syncthreads();
    tmp[t] += u;
    __syncthreads();
  }
  if (t < SCAN_NB) bsum[t] = tmp[t] - v;
  if (t == 127) offs[N_NODES] = tmp[127];
}

__global__ __launch_bounds__(512) void k_scan3(const int* __restrict__ cnt, const int* __restrict__ excl,
                                               const int* __restrict__ bsum, int* __restrict__ offs,
                                               int* __restrict__ cursor, float* __restrict__ dinv) {
  const int i = blockIdx.x * 512 + threadIdx.x;
  if (i >= N_NODES) return;
  int o = excl[i] + bsum[blockIdx.x];
  offs[i] = o;
  cursor[i] = o;
  dinv[i] = 1.0f / sqrtf((float)(cnt[i] + 1));
}

// ---------------- scatter edges into CSR buckets (uint16 src) ----------------
__global__ void k_fill(const int* __restrict__ row, const int* __restrict__ col, int E,
                       int* __restrict__ cursor, unsigned short* __restrict__ csr_src) {
  int e = blockIdx.x * blockDim.x + threadIdx.x;
  if (e >= E) return;
  int pos = atomicAdd(&cursor[col[e]], 1);
  csr_src[pos] = (unsigned short)row[e];
}

// ---------------- MFMA GEMM: Y[M,128] = A @ W; LDS epilogue, row-major bf16 out ----------------
// SCALE: multiply output row r by dinv[r] (g = dinv*hW).
template <bool AF32, bool BIAS, bool RELU, bool SCALE>
__global__ __launch_bounds__(256) void k_gemm_mfma(const void* __restrict__ Av,
                                                   const unsigned short* __restrict__ Wt,
                                                   const float* __restrict__ bias,
                                                   const float* __restrict__ dinv,
                                                   unsigned short* __restrict__ Y, int M) {
  __shared__ float ys[64][132];
  const int wave = threadIdx.x >> 6;
  const int lane = threadIdx.x & 63;
  const int row16 = (blockIdx.x * 4 + wave) * 16;
  const int lr = lane & 15;
  const int lk = (lane >> 4) * 8;

  f32x4 acc[8];
#pragma unroll
  for (int i = 0; i < 8; ++i) acc[i] = (f32x4){0.f, 0.f, 0.f, 0.f};

  const int arow = min(row16 + lr, M - 1);   // clamp; stores guarded
#pragma unroll
  for (int ks = 0; ks < 4; ++ks) {
    const int k0 = ks * 32 + lk;
    bf16x8 a;
    if (AF32) {
      const float* Af = (const float*)Av;
      float4 f0 = *(const float4*)(Af + (size_t)arow * HID + k0);
      float4 f1 = *(const float4*)(Af + (size_t)arow * HID + k0 + 4);
      ushort8 u;
      u[0] = f2bf(f0.x); u[1] = f2bf(f0.y); u[2] = f2bf(f0.z); u[3] = f2bf(f0.w);
      u[4] = f2bf(f1.x); u[5] = f2bf(f1.y); u[6] = f2bf(f1.z); u[7] = f2bf(f1.w);
      a = __builtin_bit_cast(bf16x8, u);
    } else {
      const unsigned short* Ab = (const unsigned short*)Av;
      a = *(const bf16x8*)(Ab + (size_t)arow * HID + k0);
    }
#pragma unroll
    for (int nt = 0; nt < 8; ++nt) {
      bf16x8 b = *(const bf16x8*)(Wt + (size_t)(nt * 16 + lr) * HID + k0);
      acc[nt] = __builtin_amdgcn_mfma_f32_16x16x32_bf16(a, b, acc[nt], 0, 0, 0);
    }
  }

  // acc -> LDS.  D layout: col = lane&15, row = (lane>>4)*4 + r
  const int wrow = wave * 16 + (lane >> 4) * 4;
#pragma unroll
  for (int nt = 0; nt < 8; ++nt) {
    const int c = nt * 16 + lr;
#pragma unroll
    for (int r = 0; r < 4; ++r) ys[wrow + r][c] = acc[nt][r];
  }
  __syncthreads();

  // epilogue: thread t -> row t>>2, full 32-col strip q = t&3 (4x ushort8 = 64B coalesced)
  const int er = threadIdx.x >> 2;
  const int q = threadIdx.x & 3;
  const int grow = blockIdx.x * 64 + er;
  if (grow < M) {
    float scale = SCALE ? dinv[grow] : 1.f;
    ushort8 pk[4];
#pragma unroll
    for (int h = 0; h < 4; ++h) {
#pragma unroll
      for (int j = 0; j < 8; ++j) {
        int c = q * 32 + h * 8 + j;
        float v = ys[er][c];
        if (BIAS) v += bias[c];
        if (RELU) v = fmaxf(v, 0.f);
        if (SCALE) v *= scale;
        pk[h][j] = f2bf(v);
      }
    }
    unsigned short* dst = Y + (size_t)grow * HID + q * 32;
    *(ushort8*)(dst)      = pk[0];
    *(ushort8*)(dst + 8)  = pk[1];
    *(ushort8*)(dst + 16) = pk[2];
    *(ushort8*)(dst + 24) = pk[3];
  }
}

// ---------------- aggregation: wave/node, 4 edge-slots x 16 lanes x uint4 (16B) ----------------
__global__ __launch_bounds__(256) void k_agg(const unsigned short* __restrict__ g, const int* __restrict__ offs,
                                             const unsigned short* __restrict__ csr_src,
                                             const float* __restrict__ dinv,
                                             const float* __restrict__ bias, unsigned short* __restrict__ out) {
  const int wave = threadIdx.x >> 6;
  const int lane = threadIdx.x & 63;
  const int v = blockIdx.x * 4 + wave;
  if (v >= N_NODES) return;
  const int s = lane >> 4;          // edge slot 0..3
  const int c = lane & 15;          // 16B chunk within 256B row

  const uint4* g4 = (const uint4*)g;   // row = 16 x uint4

  float a0 = 0.f, a1 = 0.f, a2 = 0.f, a3 = 0.f, a4 = 0.f, a5 = 0.f, a6 = 0.f, a7 = 0.f;
  if (s == 0) {                        // self term in slot 0
    uint4 m = g4[(size_t)v * 16 + c];
    a0 = ulo(m.x); a1 = uhi(m.x); a2 = ulo(m.y); a3 = uhi(m.y);
    a4 = ulo(m.z); a5 = uhi(m.z); a6 = ulo(m.w); a7 = uhi(m.w);
  }

  const int lo = offs[v], hi = offs[v + 1];
  int idx = lo + s;
  for (; idx + 4 < hi; idx += 8) {
    int s0 = csr_src[idx];
    int s1 = csr_src[idx + 4];
    uint4 m0 = g4[(size_t)s0 * 16 + c];
    uint4 m1 = g4[(size_t)s1 * 16 + c];
    a0 += ulo(m0.x) + ulo(m1.x); a1 += uhi(m0.x) + uhi(m1.x);
    a2 += ulo(m0.y) + ulo(m1.y); a3 += uhi(m0.y) + uhi(m1.y);
    a4 += ulo(m0.z) + ulo(m1.z); a5 += uhi(m0.z) + uhi(m1.z);
    a6 += ulo(m0.w) + ulo(m1.w); a7 += uhi(m0.w) + uhi(m1.w);
  }
  if (idx < hi) {
    uint4 m0 = g4[(size_t)csr_src[idx] * 16 + c];
    a0 += ulo(m0.x); a1 += uhi(m0.x);
    a2 += ulo(m0.y); a3 += uhi(m0.y);
    a4 += ulo(m0.z); a5 += uhi(m0.z);
    a6 += ulo(m0.w); a7 += uhi(m0.w);
  }

  a0 += __shfl_xor(a0, 16, 64); a0 += __shfl_xor(a0, 32, 64);
  a1 += __shfl_xor(a1, 16, 64); a1 += __shfl_xor(a1, 32, 64);
  a2 += __shfl_xor(a2, 16, 64); a2 += __shfl_xor(a2, 32, 64);
  a3 += __shfl_xor(a3, 16, 64); a3 += __shfl_xor(a3, 32, 64);
  a4 += __shfl_xor(a4, 16, 64); a4 += __shfl_xor(a4, 32, 64);
  a5 += __shfl_xor(a5, 16, 64); a5 += __shfl_xor(a5, 32, 64);
  a6 += __shfl_xor(a6, 16, 64); a6 += __shfl_xor(a6, 32, 64);
  a7 += __shfl_xor(a7, 16, 64); a7 += __shfl_xor(a7, 32, 64);

  if (s == 0) {
    const float d = dinv[v];
    float4 b0 = ((const float4*)bias)[c * 2];
    float4 b1 = ((const float4*)bias)[c * 2 + 1];
    float o0 = fmaxf(d * a0 + b0.x, 0.f), o1 = fmaxf(d * a1 + b0.y, 0.f);
    float o2 = fmaxf(d * a2 + b0.z, 0.f), o3 = fmaxf(d * a3 + b0.w, 0.f);
    float o4 = fmaxf(d * a4 + b1.x, 0.f), o5 = fmaxf(d * a5 + b1.y, 0.f);
    float o6 = fmaxf(d * a6 + b1.z, 0.f), o7 = fmaxf(d * a7 + b1.w, 0.f);
    uint4 pk;
    pk.x = (unsigned)f2bf(o0) | ((unsigned)f2bf(o1) << 16);
    pk.y = (unsigned)f2bf(o2) | ((unsigned)f2bf(o3) << 16);
    pk.z = (unsigned)f2bf(o4) | ((unsigned)f2bf(o5) << 16);
    pk.w = (unsigned)f2bf(o6) | ((unsigned)f2bf(o7) << 16);
    ((uint4*)out)[(size_t)v * 16 + c] = pk;
  }
}

// ---------------- FUSED agg + next-layer gemm ----------------
// Block = 512 threads (8 waves), 64 nodes. Phase A: each wave runs the proven
// single-node agg body 8x; slot-0 packs h-row (bf16) into LDS (no global h).
// Phase B: gemm on the 64-row LDS tile -> gout = dinv * (h @ W), row-major.
// No global sync needed: gathers read g (prev buffer), writes go to gout rows of THIS block.
__global__ __launch_bounds__(512) void k_agggemm(const unsigned short* __restrict__ g,
                                                 const int* __restrict__ offs,
                                                 const unsigned short* __restrict__ csr_src,
                                                 const float* __restrict__ dinv,
                                                 const float* __restrict__ bias,
                                                 const unsigned short* __restrict__ Wt,
                                                 unsigned short* __restrict__ gout) {
  __shared__ unsigned short hs[64][136];     // 136-pad: 272B rows, 16B-aligned
  const int wid = threadIdx.x >> 6;
  const int lane = threadIdx.x & 63;
  const int s = lane >> 4;
  const int c = lane & 15;
  const int tile = blockIdx.x * 64;
  const uint4* g4 = (const uint4*)g;

  // ---- Phase A: aggregate 8 nodes per wave (R15 body verbatim) ----
  for (int it = 0; it < 8; ++it) {
    const int vloc = wid * 8 + it;
    const int v = tile + vloc;
    if (v >= N_NODES) break;

    float a0 = 0.f, a1 = 0.f, a2 = 0.f, a3 = 0.f, a4 = 0.f, a5 = 0.f, a6 = 0.f, a7 = 0.f;
    if (s == 0) {
      uint4 m = g4[(size_t)v * 16 + c];
      a0 = ulo(m.x); a1 = uhi(m.x); a2 = ulo(m.y); a3 = uhi(m.y);
      a4 = ulo(m.z); a5 = uhi(m.z); a6 = ulo(m.w); a7 = uhi(m.w);
    }
    const int lo = offs[v], hi = offs[v + 1];
    int idx = lo + s;
    for (; idx + 4 < hi; idx += 8) {
      int s0 = csr_src[idx];
      int s1 = csr_src[idx + 4];
      uint4 m0 = g4[(size_t)s0 * 16 + c];
      uint4 m1 = g4[(size_t)s1 * 16 + c];
      a0 += ulo(m0.x) + ulo(m1.x); a1 += uhi(m0.x) + uhi(m1.x);
      a2 += ulo(m0.y) + ulo(m1.y); a3 += uhi(m0.y) + uhi(m1.y);
      a4 += ulo(m0.z) + ulo(m1.z); a5 += uhi(m0.z) + uhi(m1.z);
      a6 += ulo(m0.w) + ulo(m1.w); a7 += uhi(m0.w) + uhi(m1.w);
    }
    if (idx < hi) {
      uint4 m0 = g4[(size_t)csr_src[idx] * 16 + c];
      a0 += ulo(m0.x); a1 += uhi(m0.x);
      a2 += ulo(m0.y); a3 += uhi(m0.y);
      a4 += ulo(m0.z); a5 += uhi(m0.z);
      a6 += ulo(m0.w); a7 += uhi(m0.w);
    }
    a0 += __shfl_xor(a0, 16, 64); a0 += __shfl_xor(a0, 32, 64);
    a1 += __shfl_xor(a1, 16, 64); a1 += __shfl_xor(a1, 32, 64);
    a2 += __shfl_xor(a2, 16, 64); a2 += __shfl_xor(a2, 32, 64);
    a3 += __shfl_xor(a3, 16, 64); a3 += __shfl_xor(a3, 32, 64);
    a4 += __shfl_xor(a4, 16, 64); a4 += __shfl_xor(a4, 32, 64);
    a5 += __shfl_xor(a5, 16, 64); a5 += __shfl_xor(a5, 32, 64);
    a6 += __shfl_xor(a6, 16, 64); a6 += __shfl_xor(a6, 32, 64);
    a7 += __shfl_xor(a7, 16, 64); a7 += __shfl_xor(a7, 32, 64);

    if (s == 0) {
      const float d = dinv[v];
      float4 b0 = ((const float4*)bias)[c * 2];
      float4 b1 = ((const float4*)bias)[c * 2 + 1];
      float o0 = fmaxf(d * a0 + b0.x, 0.f), o1 = fmaxf(d * a1 + b0.y, 0.f);
      float o2 = fmaxf(d * a2 + b0.z, 0.f), o3 = fmaxf(d * a3 + b0.w, 0.f);
      float o4 = fmaxf(d * a4 + b1.x, 0.f), o5 = fmaxf(d * a5 + b1.y, 0.f);
      float o6 = fmaxf(d * a6 + b1.z, 0.f), o7 = fmaxf(d * a7 + b1.w, 0.f);
      uint4 pk;
      pk.x = (unsigned)f2bf(o0) | ((unsigned)f2bf(o1) << 16);
      pk.y = (unsigned)f2bf(o2) | ((unsigned)f2bf(o3) << 16);
      pk.z = (unsigned)f2bf(o4) | ((unsigned)f2bf(o5) << 16);
      pk.w = (unsigned)f2bf(o6) | ((unsigned)f2bf(o7) << 16);
      *(uint4*)&hs[vloc][c * 8] = pk;     // 16B-aligned (row 272B, c*8 shorts)
    }
  }
  __syncthreads();

  // ---- Phase B: gemm on the 64x128 LDS h-tile -> gout = dinv * (h @ W) ----
  const int mt = wid & 3;          // M-tile 0..3 (16 rows each)
  const int nb = (wid >> 2) * 4;   // N-tiles nb..nb+3
  const int lr = lane & 15;
  const int lk = (lane >> 4) * 8;

  f32x4 acc[4];
#pragma unroll
  for (int j = 0; j < 4; ++j) acc[j] = (f32x4){0.f, 0.f, 0.f, 0.f};

#pragma unroll
  for (int ks = 0; ks < 4; ++ks) {
    const int k0 = ks * 32 + lk;
    bf16x8 a = *(const bf16x8*)&hs[mt * 16 + lr][k0];
#pragma unroll
    for (int j = 0; j < 4; ++j) {
      bf16x8 b = *(const bf16x8*)(Wt + (size_t)((nb + j) * 16 + lr) * HID + k0);
      acc[j] = __builtin_amdgcn_mfma_f32_16x16x32_bf16(a, b, acc[j], 0, 0, 0);
    }
  }

  // D layout: col = lane&15, row = (lane>>4)*4 + r
  const int drow = tile + mt * 16 + (lane >> 4) * 4;
#pragma unroll
  for (int j = 0; j < 4; ++j) {
    const int gcol = (nb + j) * 16 + lr;
#pragma unroll
    for (int r = 0; r < 4; ++r) {
      const int rr = drow + r;
      if (rr < N_NODES) gout[(size_t)rr * HID + gcol] = f2bf(acc[j][r] * dinv[rr]);
    }
  }
}

// ---------------- fused mean pool + heads ----------------
__global__ __launch_bounds__(1024) void k_poolheads(const unsigned short* __restrict__ h,
                                                    const int* __restrict__ gstart, const int* __restrict__ gend,
                                                    const float* __restrict__ W0, const float* __restrict__ b0,
                                                    const float* __restrict__ W1, const float* __restrict__ b1,
                                                    const float* __restrict__ W2, const float* __restrict__ b2,
                                                    float* __restrict__ out) {
  __shared__ float red[1024];
  __shared__ float pm[HID];
  const int g = blockIdx.x;
  const int tid = threadIdx.x;
  const int j = tid & 127;
  const int r0 = tid >> 7;
  const int lo = gstart[g], hi = gend[g];
  float acc = 0.f;
  for (int v = lo + r0; v < hi; v += 8) acc += bf2f(h[(size_t)v * HID + j]);
  red[tid] = acc;
  __syncthreads();
  if (r0 < 4) red[tid] += red[tid + 512];
  __syncthreads();
  if (r0 < 2) red[tid] += red[tid + 256];
  __syncthreads();
  if (r0 < 1) {
    float s = red[tid] + red[tid + 128];
    pm[j] = s / fmaxf((float)(hi - lo), 1.f);
  }
  __syncthreads();
  if (tid < 384) {
    const int t = tid >> 7;        // head 0..2
    const int cc = tid & 127;      // col
    const float* W = (t == 0) ? W0 : ((t == 1) ? W1 : W2);
    const float* b = (t == 0) ? b0 : ((t == 1) ? b1 : b2);
    float a2 = 0.f;
#pragma unroll 8
    for (int k = 0; k < HID; ++k) a2 += pm[k] * W[k * HID + cc];
    out[((size_t)t * NGRAPH + g) * HID + cc] = a2 + b[cc];
  }
}

extern "C" void kernel_launch(void* const* d_in, const int* in_sizes, int n_in,
                              void* d_out, int out_size, void* d_ws, size_t ws_size,
                              hipStream_t stream) {
  const float* x     = (const float*)d_in[0];
  const int*   ei    = (const int*)d_in[1];
  const int*   batch = (const int*)d_in[2];
  const float* W_in  = (const float*)d_in[3];
  const float* b_in  = (const float*)d_in[4];
  const float* convW = (const float*)d_in[5];
  const float* convb = (const float*)d_in[6];
  const float* W_def = (const float*)d_in[7];
  const float* b_def = (const float*)d_in[8];
  const float* W_syn = (const float*)d_in[9];
  const float* b_syn = (const float*)d_in[10];
  const float* W_rel = (const float*)d_in[11];
  const float* b_rel = (const float*)d_in[12];

  const int E = in_sizes[1] / 2;  // 640000
  const int* row = ei;            // source
  const int* col = ei + E;        // target

  char* base = (char*)d_ws;
  size_t off = 0;
  auto alloc = [&](size_t bytes) -> void* {
    void* p = base + off;
    off += (bytes + 255) & ~size_t(255);
    return p;
  };
  int*   cnt     = (int*)  alloc((size_t)N_NODES * 4);
  float* dinv    = (float*)alloc((size_t)N_NODES * 4);
  int*   offs    = (int*)  alloc((size_t)(N_NODES + 1) * 4);
  int*   cursor  = (int*)  alloc((size_t)N_NODES * 4);
  int*   excl    = (int*)  alloc((size_t)N_NODES * 4);
  int*   bsum    = (int*)  alloc((size_t)SCAN_NB * 4);
  unsigned short* csr_src = (unsigned short*)alloc((size_t)E * 2);
  unsigned short* hA = (unsigned short*)alloc((size_t)N_NODES * HID * 2);  // bf16 h0 / h4
  unsigned short* hB = (unsigned short*)alloc((size_t)N_NODES * HID * 2);  // bf16 g (ping)
  unsigned short* hC = (unsigned short*)alloc((size_t)N_NODES * HID * 2);  // bf16 g (pong)
  unsigned short* WtAll = (unsigned short*)alloc((size_t)5 * HID * HID * 2);
  int*   gstart  = (int*)  alloc((size_t)NGRAPH * 4);
  int*   gend    = (int*)  alloc((size_t)NGRAPH * 4);

  // graph preprocessing
  k_init<<<(N_NODES + 255) / 256, 256, 0, stream>>>(cnt, gstart, gend);
  k_hist<<<HIST_NB + WPREP_NB, 256, 0, stream>>>(col, E, cnt, batch, gstart, gend, W_in, convW, WtAll);
  k_scan1<<<SCAN_NB, 512, 0, stream>>>(cnt, excl, bsum);
  k_scan2<<<1, 128, 0, stream>>>(bsum, offs);
  k_scan3<<<SCAN_NB, 512, 0, stream>>>(cnt, excl, bsum, offs, cursor, dinv);
  k_fill<<<(E + 255) / 256, 256, 0, stream>>>(row, col, E, cursor, csr_src);

  const int gemm_grid = (N_NODES + 63) / 64;
  // h0 = relu(x @ W_in + b_in)
  k_gemm_mfma<true, true, true, false><<<gemm_grid, 256, 0, stream>>>(x, WtAll, b_in, nullptr, hA, N_NODES);
  // g0 = dinv * (h0 @ convW[0])
  k_gemm_mfma<false, false, false, true><<<gemm_grid, 256, 0, stream>>>(
      hA, WtAll + (size_t)1 * HID * HID, nullptr, dinv, hB, N_NODES);

  // layers 0..2: fused agg(g_i) -> h_{i+1} (LDS only) -> g_{i+1} = dinv*(h @ convW[i+1])
  unsigned short* gin = hB;
  unsigned short* gout = hC;
  for (int i = 0; i < 3; ++i) {
    k_agggemm<<<gemm_grid, 512, 0, stream>>>(gin, offs, csr_src, dinv,
                                             convb + (size_t)i * HID,
                                             WtAll + (size_t)(i + 2) * HID * HID, gout);
    unsigned short* t = gin; gin = gout; gout = t;
  }

  // last layer: h4 = relu(dinv*agg(g3) + convb[3])  (row-major for pooling)
  k_agg<<<(N_NODES + 3) / 4, 256, 0, stream>>>(gin, offs, csr_src, dinv,
                                               convb + (size_t)3 * HID, hA);

  k_poolheads<<<NGRAPH, 1024, 0, stream>>>(hA, gstart, gend, W_def, b_def, W_syn, b_syn, W_rel, b_rel,
                                           (float*)d_out);
}

// Round 17
// 320.270 us; speedup vs baseline: 1.1687x; 1.0181x over previous
//
#include <hip/hip_runtime.h>
#include <hip/hip_bf16.h>

#define N_NODES 50000
#define NGRAPH 64
#define HID 128
#define NLAYERS 4
#define SCAN_NB ((N_NODES + 511) / 512)   // 98 blocks
#define HIST_NB 2500                      // ceil(640000/256)
#define WPREP_NB 320                      // ceil(5*128*128/256)

typedef __attribute__((ext_vector_type(8))) __bf16 bf16x8;
typedef __attribute__((ext_vector_type(8))) unsigned short ushort8;
typedef __attribute__((ext_vector_type(4))) float f32x4;

__device__ __forceinline__ float bf2f(unsigned short u) { return __uint_as_float(((unsigned)u) << 16); }
__device__ __forceinline__ unsigned short f2bf(float f) { return __hip_bfloat16_raw(__float2bfloat16(f)).x; }
__device__ __forceinline__ float ulo(unsigned m) { return __uint_as_float(m << 16); }
__device__ __forceinline__ float uhi(unsigned m) { return __uint_as_float(m & 0xffff0000u); }

// ---------------- init: zero histogram + graph bounds ----------------
__global__ void k_init(int* __restrict__ cnt, int* __restrict__ gstart, int* __restrict__ gend) {
  int i = blockIdx.x * blockDim.x + threadIdx.x;
  if (i < N_NODES) cnt[i] = 0;
  if (i < NGRAPH) { gstart[i] = 0; gend[i] = 0; }
}

// ---------------- fused: histogram over target + graph bounds + weight prep ----------------
__global__ void k_hist(const int* __restrict__ col, int E, int* __restrict__ cnt,
                       const int* __restrict__ batch, int* __restrict__ gstart, int* __restrict__ gend,
                       const float* __restrict__ Win, const float* __restrict__ Wconv,
                       unsigned short* __restrict__ WtAll) {
  if (blockIdx.x < HIST_NB) {
    int e = blockIdx.x * blockDim.x + threadIdx.x;
    if (e < E) atomicAdd(&cnt[col[e]], 1);
    if (e < N_NODES) {
      int b = batch[e];
      if (e == 0 || batch[e - 1] != b) gstart[b] = e;
      if (e == N_NODES - 1 || batch[e + 1] != b) gend[b] = e + 1;
    }
  } else {
    int idx = (blockIdx.x - HIST_NB) * 256 + threadIdx.x;
    if (idx >= 5 * HID * HID) return;
    int m = idx >> 14, rem = idx & 16383;
    int k = rem >> 7, n = rem & 127;
    const float* src = (m == 0) ? Win : (Wconv + (size_t)(m - 1) * HID * HID);
    WtAll[(size_t)m * HID * HID + n * HID + k] = f2bf(src[k * HID + n]);
  }
}

// ---------------- multi-block scan ----------------
__global__ __launch_bounds__(512) void k_scan1(const int* __restrict__ cnt, int* __restrict__ excl,
                                               int* __restrict__ bsum) {
  __shared__ int tmp[512];
  const int t = threadIdx.x;
  const int i = blockIdx.x * 512 + t;
  int v = (i < N_NODES) ? cnt[i] : 0;
  tmp[t] = v;
  __syncthreads();
#pragma unroll
  for (int off = 1; off < 512; off <<= 1) {
    int u = (t >= off) ? tmp[t - off] : 0;
    __syncthreads();
    tmp[t] += u;
    __syncthreads();
  }
  if (i < N_NODES) excl[i] = tmp[t] - v;
  if (t == 511) bsum[blockIdx.x] = tmp[511];
}

__global__ __launch_bounds__(128) void k_scan2(int* __restrict__ bsum, int* __restrict__ offs) {
  __shared__ int tmp[128];
  const int t = threadIdx.x;
  int v = (t < SCAN_NB) ? bsum[t] : 0;
  tmp[t] = v;
  __syncthreads();
#pragma unroll
  for (int off = 1; off < 128; off <<= 1) {
    int u = (t >= off) ? tmp[t - off] : 0;
    __syncthreads();
    tmp[t] += u;
    __syncthreads();
  }
  if (t < SCAN_NB) bsum[t] = tmp[t] - v;
  if (t == 127) offs[N_NODES] = tmp[127];
}

__global__ __launch_bounds__(512) void k_scan3(const int* __restrict__ cnt, const int* __restrict__ excl,
                                               const int* __restrict__ bsum, int* __restrict__ offs,
                                               int* __restrict__ cursor, float* __restrict__ dinv) {
  const int i = blockIdx.x * 512 + threadIdx.x;
  if (i >= N_NODES) return;
  int o = excl[i] + bsum[blockIdx.x];
  offs[i] = o;
  cursor[i] = o;
  dinv[i] = 1.0f / sqrtf((float)(cnt[i] + 1));
}

// ---------------- scatter edges into CSR buckets (uint16 src) ----------------
__global__ void k_fill(const int* __restrict__ row, const int* __restrict__ col, int E,
                       int* __restrict__ cursor, unsigned short* __restrict__ csr_src) {
  int e = blockIdx.x * blockDim.x + threadIdx.x;
  if (e >= E) return;
  int pos = atomicAdd(&cursor[col[e]], 1);
  csr_src[pos] = (unsigned short)row[e];
}

// ---------------- FUSED prologue: h0 = relu(x@W_in+b) in LDS -> g0 = dinv*(h0@convW0) ----------------
// Block = 512 threads (8 waves), 64 rows. Phase A: MFMA from f32 x (bf16 in-register),
// bias+relu, bf16 into LDS (identical rounding to the old global path). Phase B: verbatim
// k_agggemm phase B.
__global__ __launch_bounds__(512) void k_gemm01(const float* __restrict__ x,
                                                const unsigned short* __restrict__ Wt0,
                                                const float* __restrict__ b_in,
                                                const unsigned short* __restrict__ Wt1,
                                                const float* __restrict__ dinv,
                                                unsigned short* __restrict__ gout) {
  __shared__ unsigned short hs[64][136];     // 136-pad: 272B rows, 16B-aligned
  const int wid = threadIdx.x >> 6;
  const int lane = threadIdx.x & 63;
  const int tile = blockIdx.x * 64;
  const int lr = lane & 15;
  const int lk = (lane >> 4) * 8;
  const int mt = wid & 3;          // M-tile 0..3
  const int nb = (wid >> 2) * 4;   // N-tiles nb..nb+3

  // ---- Phase A: h0 tile ----
  f32x4 acc[4];
#pragma unroll
  for (int j = 0; j < 4; ++j) acc[j] = (f32x4){0.f, 0.f, 0.f, 0.f};

  const int arow = min(tile + mt * 16 + lr, N_NODES - 1);
#pragma unroll
  for (int ks = 0; ks < 4; ++ks) {
    const int k0 = ks * 32 + lk;
    float4 f0 = *(const float4*)(x + (size_t)arow * HID + k0);
    float4 f1 = *(const float4*)(x + (size_t)arow * HID + k0 + 4);
    ushort8 u;
    u[0] = f2bf(f0.x); u[1] = f2bf(f0.y); u[2] = f2bf(f0.z); u[3] = f2bf(f0.w);
    u[4] = f2bf(f1.x); u[5] = f2bf(f1.y); u[6] = f2bf(f1.z); u[7] = f2bf(f1.w);
    bf16x8 a = __builtin_bit_cast(bf16x8, u);
#pragma unroll
    for (int j = 0; j < 4; ++j) {
      bf16x8 b = *(const bf16x8*)(Wt0 + (size_t)((nb + j) * 16 + lr) * HID + k0);
      acc[j] = __builtin_amdgcn_mfma_f32_16x16x32_bf16(a, b, acc[j], 0, 0, 0);
    }
  }
  // D layout: col = lane&15, row = (lane>>4)*4 + r ; bias+relu, bf16 -> LDS
  const int drloc = mt * 16 + (lane >> 4) * 4;
#pragma unroll
  for (int j = 0; j < 4; ++j) {
    const int gcol = (nb + j) * 16 + lr;
    const float bv = b_in[gcol];
#pragma unroll
    for (int r = 0; r < 4; ++r)
      hs[drloc + r][gcol] = f2bf(fmaxf(acc[j][r] + bv, 0.f));
  }
  __syncthreads();

  // ---- Phase B: g0 = dinv * (h0 @ convW0) ----
#pragma unroll
  for (int j = 0; j < 4; ++j) acc[j] = (f32x4){0.f, 0.f, 0.f, 0.f};

#pragma unroll
  for (int ks = 0; ks < 4; ++ks) {
    const int k0 = ks * 32 + lk;
    bf16x8 a = *(const bf16x8*)&hs[mt * 16 + lr][k0];
#pragma unroll
    for (int j = 0; j < 4; ++j) {
      bf16x8 b = *(const bf16x8*)(Wt1 + (size_t)((nb + j) * 16 + lr) * HID + k0);
      acc[j] = __builtin_amdgcn_mfma_f32_16x16x32_bf16(a, b, acc[j], 0, 0, 0);
    }
  }
  const int drow = tile + mt * 16 + (lane >> 4) * 4;
#pragma unroll
  for (int j = 0; j < 4; ++j) {
    const int gcol = (nb + j) * 16 + lr;
#pragma unroll
    for (int r = 0; r < 4; ++r) {
      const int rr = drow + r;
      if (rr < N_NODES) gout[(size_t)rr * HID + gcol] = f2bf(acc[j][r] * dinv[rr]);
    }
  }
}

// ---------------- aggregation: wave/node, 4 edge-slots x 16 lanes x uint4 (16B) ----------------
__global__ __launch_bounds__(256) void k_agg(const unsigned short* __restrict__ g, const int* __restrict__ offs,
                                             const unsigned short* __restrict__ csr_src,
                                             const float* __restrict__ dinv,
                                             const float* __restrict__ bias, unsigned short* __restrict__ out) {
  const int wave = threadIdx.x >> 6;
  const int lane = threadIdx.x & 63;
  const int v = blockIdx.x * 4 + wave;
  if (v >= N_NODES) return;
  const int s = lane >> 4;          // edge slot 0..3
  const int c = lane & 15;          // 16B chunk within 256B row

  const uint4* g4 = (const uint4*)g;   // row = 16 x uint4

  float a0 = 0.f, a1 = 0.f, a2 = 0.f, a3 = 0.f, a4 = 0.f, a5 = 0.f, a6 = 0.f, a7 = 0.f;
  if (s == 0) {                        // self term in slot 0
    uint4 m = g4[(size_t)v * 16 + c];
    a0 = ulo(m.x); a1 = uhi(m.x); a2 = ulo(m.y); a3 = uhi(m.y);
    a4 = ulo(m.z); a5 = uhi(m.z); a6 = ulo(m.w); a7 = uhi(m.w);
  }

  const int lo = offs[v], hi = offs[v + 1];
  int idx = lo + s;
  for (; idx + 4 < hi; idx += 8) {
    int s0 = csr_src[idx];
    int s1 = csr_src[idx + 4];
    uint4 m0 = g4[(size_t)s0 * 16 + c];
    uint4 m1 = g4[(size_t)s1 * 16 + c];
    a0 += ulo(m0.x) + ulo(m1.x); a1 += uhi(m0.x) + uhi(m1.x);
    a2 += ulo(m0.y) + ulo(m1.y); a3 += uhi(m0.y) + uhi(m1.y);
    a4 += ulo(m0.z) + ulo(m1.z); a5 += uhi(m0.z) + uhi(m1.z);
    a6 += ulo(m0.w) + ulo(m1.w); a7 += uhi(m0.w) + uhi(m1.w);
  }
  if (idx < hi) {
    uint4 m0 = g4[(size_t)csr_src[idx] * 16 + c];
    a0 += ulo(m0.x); a1 += uhi(m0.x);
    a2 += ulo(m0.y); a3 += uhi(m0.y);
    a4 += ulo(m0.z); a5 += uhi(m0.z);
    a6 += ulo(m0.w); a7 += uhi(m0.w);
  }

  a0 += __shfl_xor(a0, 16, 64); a0 += __shfl_xor(a0, 32, 64);
  a1 += __shfl_xor(a1, 16, 64); a1 += __shfl_xor(a1, 32, 64);
  a2 += __shfl_xor(a2, 16, 64); a2 += __shfl_xor(a2, 32, 64);
  a3 += __shfl_xor(a3, 16, 64); a3 += __shfl_xor(a3, 32, 64);
  a4 += __shfl_xor(a4, 16, 64); a4 += __shfl_xor(a4, 32, 64);
  a5 += __shfl_xor(a5, 16, 64); a5 += __shfl_xor(a5, 32, 64);
  a6 += __shfl_xor(a6, 16, 64); a6 += __shfl_xor(a6, 32, 64);
  a7 += __shfl_xor(a7, 16, 64); a7 += __shfl_xor(a7, 32, 64);

  if (s == 0) {
    const float d = dinv[v];
    float4 b0 = ((const float4*)bias)[c * 2];
    float4 b1 = ((const float4*)bias)[c * 2 + 1];
    float o0 = fmaxf(d * a0 + b0.x, 0.f), o1 = fmaxf(d * a1 + b0.y, 0.f);
    float o2 = fmaxf(d * a2 + b0.z, 0.f), o3 = fmaxf(d * a3 + b0.w, 0.f);
    float o4 = fmaxf(d * a4 + b1.x, 0.f), o5 = fmaxf(d * a5 + b1.y, 0.f);
    float o6 = fmaxf(d * a6 + b1.z, 0.f), o7 = fmaxf(d * a7 + b1.w, 0.f);
    uint4 pk;
    pk.x = (unsigned)f2bf(o0) | ((unsigned)f2bf(o1) << 16);
    pk.y = (unsigned)f2bf(o2) | ((unsigned)f2bf(o3) << 16);
    pk.z = (unsigned)f2bf(o4) | ((unsigned)f2bf(o5) << 16);
    pk.w = (unsigned)f2bf(o6) | ((unsigned)f2bf(o7) << 16);
    ((uint4*)out)[(size_t)v * 16 + c] = pk;
  }
}

// ---------------- FUSED agg + next-layer gemm ----------------
__global__ __launch_bounds__(512) void k_agggemm(const unsigned short* __restrict__ g,
                                                 const int* __restrict__ offs,
                                                 const unsigned short* __restrict__ csr_src,
                                                 const float* __restrict__ dinv,
                                                 const float* __restrict__ bias,
                                                 const unsigned short* __restrict__ Wt,
                                                 unsigned short* __restrict__ gout) {
  __shared__ unsigned short hs[64][136];     // 136-pad: 272B rows, 16B-aligned
  const int wid = threadIdx.x >> 6;
  const int lane = threadIdx.x & 63;
  const int s = lane >> 4;
  const int c = lane & 15;
  const int tile = blockIdx.x * 64;
  const uint4* g4 = (const uint4*)g;

  // ---- Phase A: aggregate 8 nodes per wave ----
  for (int it = 0; it < 8; ++it) {
    const int vloc = wid * 8 + it;
    const int v = tile + vloc;
    if (v >= N_NODES) break;

    float a0 = 0.f, a1 = 0.f, a2 = 0.f, a3 = 0.f, a4 = 0.f, a5 = 0.f, a6 = 0.f, a7 = 0.f;
    if (s == 0) {
      uint4 m = g4[(size_t)v * 16 + c];
      a0 = ulo(m.x); a1 = uhi(m.x); a2 = ulo(m.y); a3 = uhi(m.y);
      a4 = ulo(m.z); a5 = uhi(m.z); a6 = ulo(m.w); a7 = uhi(m.w);
    }
    const int lo = offs[v], hi = offs[v + 1];
    int idx = lo + s;
    for (; idx + 4 < hi; idx += 8) {
      int s0 = csr_src[idx];
      int s1 = csr_src[idx + 4];
      uint4 m0 = g4[(size_t)s0 * 16 + c];
      uint4 m1 = g4[(size_t)s1 * 16 + c];
      a0 += ulo(m0.x) + ulo(m1.x); a1 += uhi(m0.x) + uhi(m1.x);
      a2 += ulo(m0.y) + ulo(m1.y); a3 += uhi(m0.y) + uhi(m1.y);
      a4 += ulo(m0.z) + ulo(m1.z); a5 += uhi(m0.z) + uhi(m1.z);
      a6 += ulo(m0.w) + ulo(m1.w); a7 += uhi(m0.w) + uhi(m1.w);
    }
    if (idx < hi) {
      uint4 m0 = g4[(size_t)csr_src[idx] * 16 + c];
      a0 += ulo(m0.x); a1 += uhi(m0.x);
      a2 += ulo(m0.y); a3 += uhi(m0.y);
      a4 += ulo(m0.z); a5 += uhi(m0.z);
      a6 += ulo(m0.w); a7 += uhi(m0.w);
    }
    a0 += __shfl_xor(a0, 16, 64); a0 += __shfl_xor(a0, 32, 64);
    a1 += __shfl_xor(a1, 16, 64); a1 += __shfl_xor(a1, 32, 64);
    a2 += __shfl_xor(a2, 16, 64); a2 += __shfl_xor(a2, 32, 64);
    a3 += __shfl_xor(a3, 16, 64); a3 += __shfl_xor(a3, 32, 64);
    a4 += __shfl_xor(a4, 16, 64); a4 += __shfl_xor(a4, 32, 64);
    a5 += __shfl_xor(a5, 16, 64); a5 += __shfl_xor(a5, 32, 64);
    a6 += __shfl_xor(a6, 16, 64); a6 += __shfl_xor(a6, 32, 64);
    a7 += __shfl_xor(a7, 16, 64); a7 += __shfl_xor(a7, 32, 64);

    if (s == 0) {
      const float d = dinv[v];
      float4 b0 = ((const float4*)bias)[c * 2];
      float4 b1 = ((const float4*)bias)[c * 2 + 1];
      float o0 = fmaxf(d * a0 + b0.x, 0.f), o1 = fmaxf(d * a1 + b0.y, 0.f);
      float o2 = fmaxf(d * a2 + b0.z, 0.f), o3 = fmaxf(d * a3 + b0.w, 0.f);
      float o4 = fmaxf(d * a4 + b1.x, 0.f), o5 = fmaxf(d * a5 + b1.y, 0.f);
      float o6 = fmaxf(d * a6 + b1.z, 0.f), o7 = fmaxf(d * a7 + b1.w, 0.f);
      uint4 pk;
      pk.x = (unsigned)f2bf(o0) | ((unsigned)f2bf(o1) << 16);
      pk.y = (unsigned)f2bf(o2) | ((unsigned)f2bf(o3) << 16);
      pk.z = (unsigned)f2bf(o4) | ((unsigned)f2bf(o5) << 16);
      pk.w = (unsigned)f2bf(o6) | ((unsigned)f2bf(o7) << 16);
      *(uint4*)&hs[vloc][c * 8] = pk;
    }
  }
  __syncthreads();

  // ---- Phase B: gemm on the 64x128 LDS h-tile -> gout = dinv * (h @ W) ----
  const int mt = wid & 3;
  const int nb = (wid >> 2) * 4;
  const int lr = lane & 15;
  const int lk = (lane >> 4) * 8;

  f32x4 acc[4];
#pragma unroll
  for (int j = 0; j < 4; ++j) acc[j] = (f32x4){0.f, 0.f, 0.f, 0.f};

#pragma unroll
  for (int ks = 0; ks < 4; ++ks) {
    const int k0 = ks * 32 + lk;
    bf16x8 a = *(const bf16x8*)&hs[mt * 16 + lr][k0];
#pragma unroll
    for (int j = 0; j < 4; ++j) {
      bf16x8 b = *(const bf16x8*)(Wt + (size_t)((nb + j) * 16 + lr) * HID + k0);
      acc[j] = __builtin_amdgcn_mfma_f32_16x16x32_bf16(a, b, acc[j], 0, 0, 0);
    }
  }

  const int drow = tile + mt * 16 + (lane >> 4) * 4;
#pragma unroll
  for (int j = 0; j < 4; ++j) {
    const int gcol = (nb + j) * 16 + lr;
#pragma unroll
    for (int r = 0; r < 4; ++r) {
      const int rr = drow + r;
      if (rr < N_NODES) gout[(size_t)rr * HID + gcol] = f2bf(acc[j][r] * dinv[rr]);
    }
  }
}

// ---------------- fused mean pool + heads ----------------
__global__ __launch_bounds__(1024) void k_poolheads(const unsigned short* __restrict__ h,
                                                    const int* __restrict__ gstart, const int* __restrict__ gend,
                                                    const float* __restrict__ W0, const float* __restrict__ b0,
                                                    const float* __restrict__ W1, const float* __restrict__ b1,
                                                    const float* __restrict__ W2, const float* __restrict__ b2,
                                                    float* __restrict__ out) {
  __shared__ float red[1024];
  __shared__ float pm[HID];
  const int g = blockIdx.x;
  const int tid = threadIdx.x;
  const int j = tid & 127;
  const int r0 = tid >> 7;
  const int lo = gstart[g], hi = gend[g];
  float acc = 0.f;
  for (int v = lo + r0; v < hi; v += 8) acc += bf2f(h[(size_t)v * HID + j]);
  red[tid] = acc;
  __syncthreads();
  if (r0 < 4) red[tid] += red[tid + 512];
  __syncthreads();
  if (r0 < 2) red[tid] += red[tid + 256];
  __syncthreads();
  if (r0 < 1) {
    float s = red[tid] + red[tid + 128];
    pm[j] = s / fmaxf((float)(hi - lo), 1.f);
  }
  __syncthreads();
  if (tid < 384) {
    const int t = tid >> 7;        // head 0..2
    const int cc = tid & 127;      // col
    const float* W = (t == 0) ? W0 : ((t == 1) ? W1 : W2);
    const float* b = (t == 0) ? b0 : ((t == 1) ? b1 : b2);
    float a2 = 0.f;
#pragma unroll 8
    for (int k = 0; k < HID; ++k) a2 += pm[k] * W[k * HID + cc];
    out[((size_t)t * NGRAPH + g) * HID + cc] = a2 + b[cc];
  }
}

extern "C" void kernel_launch(void* const* d_in, const int* in_sizes, int n_in,
                              void* d_out, int out_size, void* d_ws, size_t ws_size,
                              hipStream_t stream) {
  const float* x     = (const float*)d_in[0];
  const int*   ei    = (const int*)d_in[1];
  const int*   batch = (const int*)d_in[2];
  const float* W_in  = (const float*)d_in[3];
  const float* b_in  = (const float*)d_in[4];
  const float* convW = (const float*)d_in[5];
  const float* convb = (const float*)d_in[6];
  const float* W_def = (const float*)d_in[7];
  const float* b_def = (const float*)d_in[8];
  const float* W_syn = (const float*)d_in[9];
  const float* b_syn = (const float*)d_in[10];
  const float* W_rel = (const float*)d_in[11];
  const float* b_rel = (const float*)d_in[12];

  const int E = in_sizes[1] / 2;  // 640000
  const int* row = ei;            // source
  const int* col = ei + E;        // target

  char* base = (char*)d_ws;
  size_t off = 0;
  auto alloc = [&](size_t bytes) -> void* {
    void* p = base + off;
    off += (bytes + 255) & ~size_t(255);
    return p;
  };
  int*   cnt     = (int*)  alloc((size_t)N_NODES * 4);
  float* dinv    = (float*)alloc((size_t)N_NODES * 4);
  int*   offs    = (int*)  alloc((size_t)(N_NODES + 1) * 4);
  int*   cursor  = (int*)  alloc((size_t)N_NODES * 4);
  int*   excl    = (int*)  alloc((size_t)N_NODES * 4);
  int*   bsum    = (int*)  alloc((size_t)SCAN_NB * 4);
  unsigned short* csr_src = (unsigned short*)alloc((size_t)E * 2);
  unsigned short* hA = (unsigned short*)alloc((size_t)N_NODES * HID * 2);  // bf16 h4
  unsigned short* hB = (unsigned short*)alloc((size_t)N_NODES * HID * 2);  // bf16 g (ping)
  unsigned short* hC = (unsigned short*)alloc((size_t)N_NODES * HID * 2);  // bf16 g (pong)
  unsigned short* WtAll = (unsigned short*)alloc((size_t)5 * HID * HID * 2);
  int*   gstart  = (int*)  alloc((size_t)NGRAPH * 4);
  int*   gend    = (int*)  alloc((size_t)NGRAPH * 4);

  // graph preprocessing
  k_init<<<(N_NODES + 255) / 256, 256, 0, stream>>>(cnt, gstart, gend);
  k_hist<<<HIST_NB + WPREP_NB, 256, 0, stream>>>(col, E, cnt, batch, gstart, gend, W_in, convW, WtAll);
  k_scan1<<<SCAN_NB, 512, 0, stream>>>(cnt, excl, bsum);
  k_scan2<<<1, 128, 0, stream>>>(bsum, offs);
  k_scan3<<<SCAN_NB, 512, 0, stream>>>(cnt, excl, bsum, offs, cursor, dinv);
  k_fill<<<(E + 255) / 256, 256, 0, stream>>>(row, col, E, cursor, csr_src);

  const int gemm_grid = (N_NODES + 63) / 64;
  // fused prologue: g0 = dinv * (relu(x @ W_in + b_in) @ convW[0]), h0 in LDS only
  k_gemm01<<<gemm_grid, 512, 0, stream>>>(x, WtAll, b_in, WtAll + (size_t)1 * HID * HID, dinv, hB);

  // layers 0..2: fused agg(g_i) -> h_{i+1} (LDS only) -> g_{i+1} = dinv*(h @ convW[i+1])
  unsigned short* gin = hB;
  unsigned short* gout = hC;
  for (int i = 0; i < 3; ++i) {
    k_agggemm<<<gemm_grid, 512, 0, stream>>>(gin, offs, csr_src, dinv,
                                             convb + (size_t)i * HID,
                                             WtAll + (size_t)(i + 2) * HID * HID, gout);
    unsigned short* t = gin; gin = gout; gout = t;
  }

  // last layer: h4 = relu(dinv*agg(g3) + convb[3])  (row-major for pooling)
  k_agg<<<(N_NODES + 3) / 4, 256, 0, stream>>>(gin, offs, csr_src, dinv,
                                               convb + (size_t)3 * HID, hA);

  k_poolheads<<<NGRAPH, 1024, 0, stream>>>(hA, gstart, gend, W_def, b_def, W_syn, b_syn, W_rel, b_rel,
                                           (float*)d_out);
}

// Round 18
// 296.702 us; speedup vs baseline: 1.2616x; 1.0794x over previous
//
#include <hip/hip_runtime.h>
#include <hip/hip_bf16.h>

#define N_NODES 50000
#define NGRAPH 64
#define HID 128
#define NLAYERS 4
#define SCAN_NB ((N_NODES + 511) / 512)   // 98 blocks
#define HIST_NB 2500                      // ceil(640000/256)
#define WPREP_NB 320                      // ceil(5*128*128/256)
#define GEMM_NB ((N_NODES + 63) / 64)     // 782
#define FILL_NB 1250                      // ceil(640000/512)

typedef __attribute__((ext_vector_type(8))) __bf16 bf16x8;
typedef __attribute__((ext_vector_type(8))) unsigned short ushort8;
typedef __attribute__((ext_vector_type(4))) float f32x4;

__device__ __forceinline__ float bf2f(unsigned short u) { return __uint_as_float(((unsigned)u) << 16); }
__device__ __forceinline__ unsigned short f2bf(float f) { return __hip_bfloat16_raw(__float2bfloat16(f)).x; }
__device__ __forceinline__ float ulo(unsigned m) { return __uint_as_float(m << 16); }
__device__ __forceinline__ float uhi(unsigned m) { return __uint_as_float(m & 0xffff0000u); }

// ---------------- init: zero histogram + graph bounds ----------------
__global__ void k_init(int* __restrict__ cnt, int* __restrict__ gstart, int* __restrict__ gend) {
  int i = blockIdx.x * blockDim.x + threadIdx.x;
  if (i < N_NODES) cnt[i] = 0;
  if (i < NGRAPH) { gstart[i] = 0; gend[i] = 0; }
}

// ---------------- fused: histogram over target + graph bounds + weight prep ----------------
__global__ void k_hist(const int* __restrict__ col, int E, int* __restrict__ cnt,
                       const int* __restrict__ batch, int* __restrict__ gstart, int* __restrict__ gend,
                       const float* __restrict__ Win, const float* __restrict__ Wconv,
                       unsigned short* __restrict__ WtAll) {
  if (blockIdx.x < HIST_NB) {
    int e = blockIdx.x * blockDim.x + threadIdx.x;
    if (e < E) atomicAdd(&cnt[col[e]], 1);
    if (e < N_NODES) {
      int b = batch[e];
      if (e == 0 || batch[e - 1] != b) gstart[b] = e;
      if (e == N_NODES - 1 || batch[e + 1] != b) gend[b] = e + 1;
    }
  } else {
    int idx = (blockIdx.x - HIST_NB) * 256 + threadIdx.x;
    if (idx >= 5 * HID * HID) return;
    int m = idx >> 14, rem = idx & 16383;
    int k = rem >> 7, n = rem & 127;
    const float* src = (m == 0) ? Win : (Wconv + (size_t)(m - 1) * HID * HID);
    WtAll[(size_t)m * HID * HID + n * HID + k] = f2bf(src[k * HID + n]);
  }
}

// ---------------- multi-block scan ----------------
__global__ __launch_bounds__(512) void k_scan1(const int* __restrict__ cnt, int* __restrict__ excl,
                                               int* __restrict__ bsum) {
  __shared__ int tmp[512];
  const int t = threadIdx.x;
  const int i = blockIdx.x * 512 + t;
  int v = (i < N_NODES) ? cnt[i] : 0;
  tmp[t] = v;
  __syncthreads();
#pragma unroll
  for (int off = 1; off < 512; off <<= 1) {
    int u = (t >= off) ? tmp[t - off] : 0;
    __syncthreads();
    tmp[t] += u;
    __syncthreads();
  }
  if (i < N_NODES) excl[i] = tmp[t] - v;
  if (t == 511) bsum[blockIdx.x] = tmp[511];
}

__global__ __launch_bounds__(128) void k_scan2(int* __restrict__ bsum, int* __restrict__ offs) {
  __shared__ int tmp[128];
  const int t = threadIdx.x;
  int v = (t < SCAN_NB) ? bsum[t] : 0;
  tmp[t] = v;
  __syncthreads();
#pragma unroll
  for (int off = 1; off < 128; off <<= 1) {
    int u = (t >= off) ? tmp[t - off] : 0;
    __syncthreads();
    tmp[t] += u;
    __syncthreads();
  }
  if (t < SCAN_NB) bsum[t] = tmp[t] - v;
  if (t == 127) offs[N_NODES] = tmp[127];
}

__global__ __launch_bounds__(512) void k_scan3(const int* __restrict__ cnt, const int* __restrict__ excl,
                                               const int* __restrict__ bsum, int* __restrict__ offs,
                                               int* __restrict__ cursor, float* __restrict__ dinv) {
  const int i = blockIdx.x * 512 + threadIdx.x;
  if (i >= N_NODES) return;
  int o = excl[i] + bsum[blockIdx.x];
  offs[i] = o;
  cursor[i] = o;
  dinv[i] = 1.0f / sqrtf((float)(cnt[i] + 1));
}

// ---------------- MERGED: gemm01 (blocks 0..GEMM_NB) || CSR fill (blocks GEMM_NB..) ----------------
// Independent stages co-scheduled in one dispatch: MFMA-bound gemm01 runs under the
// latency shadow of the scatter-bound fill. Both bodies verbatim from the green R17 build.
__global__ __launch_bounds__(512) void k_fillgemm(const int* __restrict__ row, const int* __restrict__ col,
                                                  int E, int* __restrict__ cursor,
                                                  unsigned short* __restrict__ csr_src,
                                                  const float* __restrict__ x,
                                                  const unsigned short* __restrict__ Wt0,
                                                  const float* __restrict__ b_in,
                                                  const unsigned short* __restrict__ Wt1,
                                                  const float* __restrict__ dinv,
                                                  unsigned short* __restrict__ gout) {
  __shared__ unsigned short hs[64][136];
  if (blockIdx.x >= GEMM_NB) {
    // ---- fill body ----
    int e = (blockIdx.x - GEMM_NB) * 512 + threadIdx.x;
    if (e < E) {
      int pos = atomicAdd(&cursor[col[e]], 1);
      csr_src[pos] = (unsigned short)row[e];
    }
    return;
  }

  // ---- gemm01 body ----
  const int wid = threadIdx.x >> 6;
  const int lane = threadIdx.x & 63;
  const int tile = blockIdx.x * 64;
  const int lr = lane & 15;
  const int lk = (lane >> 4) * 8;
  const int mt = wid & 3;
  const int nb = (wid >> 2) * 4;

  f32x4 acc[4];
#pragma unroll
  for (int j = 0; j < 4; ++j) acc[j] = (f32x4){0.f, 0.f, 0.f, 0.f};

  const int arow = min(tile + mt * 16 + lr, N_NODES - 1);
#pragma unroll
  for (int ks = 0; ks < 4; ++ks) {
    const int k0 = ks * 32 + lk;
    float4 f0 = *(const float4*)(x + (size_t)arow * HID + k0);
    float4 f1 = *(const float4*)(x + (size_t)arow * HID + k0 + 4);
    ushort8 u;
    u[0] = f2bf(f0.x); u[1] = f2bf(f0.y); u[2] = f2bf(f0.z); u[3] = f2bf(f0.w);
    u[4] = f2bf(f1.x); u[5] = f2bf(f1.y); u[6] = f2bf(f1.z); u[7] = f2bf(f1.w);
    bf16x8 a = __builtin_bit_cast(bf16x8, u);
#pragma unroll
    for (int j = 0; j < 4; ++j) {
      bf16x8 b = *(const bf16x8*)(Wt0 + (size_t)((nb + j) * 16 + lr) * HID + k0);
      acc[j] = __builtin_amdgcn_mfma_f32_16x16x32_bf16(a, b, acc[j], 0, 0, 0);
    }
  }
  const int drloc = mt * 16 + (lane >> 4) * 4;
#pragma unroll
  for (int j = 0; j < 4; ++j) {
    const int gcol = (nb + j) * 16 + lr;
    const float bv = b_in[gcol];
#pragma unroll
    for (int r = 0; r < 4; ++r)
      hs[drloc + r][gcol] = f2bf(fmaxf(acc[j][r] + bv, 0.f));
  }
  __syncthreads();

#pragma unroll
  for (int j = 0; j < 4; ++j) acc[j] = (f32x4){0.f, 0.f, 0.f, 0.f};

#pragma unroll
  for (int ks = 0; ks < 4; ++ks) {
    const int k0 = ks * 32 + lk;
    bf16x8 a = *(const bf16x8*)&hs[mt * 16 + lr][k0];
#pragma unroll
    for (int j = 0; j < 4; ++j) {
      bf16x8 b = *(const bf16x8*)(Wt1 + (size_t)((nb + j) * 16 + lr) * HID + k0);
      acc[j] = __builtin_amdgcn_mfma_f32_16x16x32_bf16(a, b, acc[j], 0, 0, 0);
    }
  }
  const int drow = tile + mt * 16 + (lane >> 4) * 4;
#pragma unroll
  for (int j = 0; j < 4; ++j) {
    const int gcol = (nb + j) * 16 + lr;
#pragma unroll
    for (int r = 0; r < 4; ++r) {
      const int rr = drow + r;
      if (rr < N_NODES) gout[(size_t)rr * HID + gcol] = f2bf(acc[j][r] * dinv[rr]);
    }
  }
}

// ---------------- aggregation: wave/node, 4 edge-slots x 16 lanes x uint4 (16B) ----------------
__global__ __launch_bounds__(256) void k_agg(const unsigned short* __restrict__ g, const int* __restrict__ offs,
                                             const unsigned short* __restrict__ csr_src,
                                             const float* __restrict__ dinv,
                                             const float* __restrict__ bias, unsigned short* __restrict__ out) {
  const int wave = threadIdx.x >> 6;
  const int lane = threadIdx.x & 63;
  const int v = blockIdx.x * 4 + wave;
  if (v >= N_NODES) return;
  const int s = lane >> 4;          // edge slot 0..3
  const int c = lane & 15;          // 16B chunk within 256B row

  const uint4* g4 = (const uint4*)g;   // row = 16 x uint4

  float a0 = 0.f, a1 = 0.f, a2 = 0.f, a3 = 0.f, a4 = 0.f, a5 = 0.f, a6 = 0.f, a7 = 0.f;
  if (s == 0) {                        // self term in slot 0
    uint4 m = g4[(size_t)v * 16 + c];
    a0 = ulo(m.x); a1 = uhi(m.x); a2 = ulo(m.y); a3 = uhi(m.y);
    a4 = ulo(m.z); a5 = uhi(m.z); a6 = ulo(m.w); a7 = uhi(m.w);
  }

  const int lo = offs[v], hi = offs[v + 1];
  int idx = lo + s;
  for (; idx + 4 < hi; idx += 8) {
    int s0 = csr_src[idx];
    int s1 = csr_src[idx + 4];
    uint4 m0 = g4[(size_t)s0 * 16 + c];
    uint4 m1 = g4[(size_t)s1 * 16 + c];
    a0 += ulo(m0.x) + ulo(m1.x); a1 += uhi(m0.x) + uhi(m1.x);
    a2 += ulo(m0.y) + ulo(m1.y); a3 += uhi(m0.y) + uhi(m1.y);
    a4 += ulo(m0.z) + ulo(m1.z); a5 += uhi(m0.z) + uhi(m1.z);
    a6 += ulo(m0.w) + ulo(m1.w); a7 += uhi(m0.w) + uhi(m1.w);
  }
  if (idx < hi) {
    uint4 m0 = g4[(size_t)csr_src[idx] * 16 + c];
    a0 += ulo(m0.x); a1 += uhi(m0.x);
    a2 += ulo(m0.y); a3 += uhi(m0.y);
    a4 += ulo(m0.z); a5 += uhi(m0.z);
    a6 += ulo(m0.w); a7 += uhi(m0.w);
  }

  a0 += __shfl_xor(a0, 16, 64); a0 += __shfl_xor(a0, 32, 64);
  a1 += __shfl_xor(a1, 16, 64); a1 += __shfl_xor(a1, 32, 64);
  a2 += __shfl_xor(a2, 16, 64); a2 += __shfl_xor(a2, 32, 64);
  a3 += __shfl_xor(a3, 16, 64); a3 += __shfl_xor(a3, 32, 64);
  a4 += __shfl_xor(a4, 16, 64); a4 += __shfl_xor(a4, 32, 64);
  a5 += __shfl_xor(a5, 16, 64); a5 += __shfl_xor(a5, 32, 64);
  a6 += __shfl_xor(a6, 16, 64); a6 += __shfl_xor(a6, 32, 64);
  a7 += __shfl_xor(a7, 16, 64); a7 += __shfl_xor(a7, 32, 64);

  if (s == 0) {
    const float d = dinv[v];
    float4 b0 = ((const float4*)bias)[c * 2];
    float4 b1 = ((const float4*)bias)[c * 2 + 1];
    float o0 = fmaxf(d * a0 + b0.x, 0.f), o1 = fmaxf(d * a1 + b0.y, 0.f);
    float o2 = fmaxf(d * a2 + b0.z, 0.f), o3 = fmaxf(d * a3 + b0.w, 0.f);
    float o4 = fmaxf(d * a4 + b1.x, 0.f), o5 = fmaxf(d * a5 + b1.y, 0.f);
    float o6 = fmaxf(d * a6 + b1.z, 0.f), o7 = fmaxf(d * a7 + b1.w, 0.f);
    uint4 pk;
    pk.x = (unsigned)f2bf(o0) | ((unsigned)f2bf(o1) << 16);
    pk.y = (unsigned)f2bf(o2) | ((unsigned)f2bf(o3) << 16);
    pk.z = (unsigned)f2bf(o4) | ((unsigned)f2bf(o5) << 16);
    pk.w = (unsigned)f2bf(o6) | ((unsigned)f2bf(o7) << 16);
    ((uint4*)out)[(size_t)v * 16 + c] = pk;
  }
}

// ---------------- FUSED agg + next-layer gemm ----------------
__global__ __launch_bounds__(512) void k_agggemm(const unsigned short* __restrict__ g,
                                                 const int* __restrict__ offs,
                                                 const unsigned short* __restrict__ csr_src,
                                                 const float* __restrict__ dinv,
                                                 const float* __restrict__ bias,
                                                 const unsigned short* __restrict__ Wt,
                                                 unsigned short* __restrict__ gout) {
  __shared__ unsigned short hs[64][136];     // 136-pad: 272B rows, 16B-aligned
  const int wid = threadIdx.x >> 6;
  const int lane = threadIdx.x & 63;
  const int s = lane >> 4;
  const int c = lane & 15;
  const int tile = blockIdx.x * 64;
  const uint4* g4 = (const uint4*)g;

  // ---- Phase A: aggregate 8 nodes per wave ----
  for (int it = 0; it < 8; ++it) {
    const int vloc = wid * 8 + it;
    const int v = tile + vloc;
    if (v >= N_NODES) break;

    float a0 = 0.f, a1 = 0.f, a2 = 0.f, a3 = 0.f, a4 = 0.f, a5 = 0.f, a6 = 0.f, a7 = 0.f;
    if (s == 0) {
      uint4 m = g4[(size_t)v * 16 + c];
      a0 = ulo(m.x); a1 = uhi(m.x); a2 = ulo(m.y); a3 = uhi(m.y);
      a4 = ulo(m.z); a5 = uhi(m.z); a6 = ulo(m.w); a7 = uhi(m.w);
    }
    const int lo = offs[v], hi = offs[v + 1];
    int idx = lo + s;
    for (; idx + 4 < hi; idx += 8) {
      int s0 = csr_src[idx];
      int s1 = csr_src[idx + 4];
      uint4 m0 = g4[(size_t)s0 * 16 + c];
      uint4 m1 = g4[(size_t)s1 * 16 + c];
      a0 += ulo(m0.x) + ulo(m1.x); a1 += uhi(m0.x) + uhi(m1.x);
      a2 += ulo(m0.y) + ulo(m1.y); a3 += uhi(m0.y) + uhi(m1.y);
      a4 += ulo(m0.z) + ulo(m1.z); a5 += uhi(m0.z) + uhi(m1.z);
      a6 += ulo(m0.w) + ulo(m1.w); a7 += uhi(m0.w) + uhi(m1.w);
    }
    if (idx < hi) {
      uint4 m0 = g4[(size_t)csr_src[idx] * 16 + c];
      a0 += ulo(m0.x); a1 += uhi(m0.x);
      a2 += ulo(m0.y); a3 += uhi(m0.y);
      a4 += ulo(m0.z); a5 += uhi(m0.z);
      a6 += ulo(m0.w); a7 += uhi(m0.w);
    }
    a0 += __shfl_xor(a0, 16, 64); a0 += __shfl_xor(a0, 32, 64);
    a1 += __shfl_xor(a1, 16, 64); a1 += __shfl_xor(a1, 32, 64);
    a2 += __shfl_xor(a2, 16, 64); a2 += __shfl_xor(a2, 32, 64);
    a3 += __shfl_xor(a3, 16, 64); a3 += __shfl_xor(a3, 32, 64);
    a4 += __shfl_xor(a4, 16, 64); a4 += __shfl_xor(a4, 32, 64);
    a5 += __shfl_xor(a5, 16, 64); a5 += __shfl_xor(a5, 32, 64);
    a6 += __shfl_xor(a6, 16, 64); a6 += __shfl_xor(a6, 32, 64);
    a7 += __shfl_xor(a7, 16, 64); a7 += __shfl_xor(a7, 32, 64);

    if (s == 0) {
      const float d = dinv[v];
      float4 b0 = ((const float4*)bias)[c * 2];
      float4 b1 = ((const float4*)bias)[c * 2 + 1];
      float o0 = fmaxf(d * a0 + b0.x, 0.f), o1 = fmaxf(d * a1 + b0.y, 0.f);
      float o2 = fmaxf(d * a2 + b0.z, 0.f), o3 = fmaxf(d * a3 + b0.w, 0.f);
      float o4 = fmaxf(d * a4 + b1.x, 0.f), o5 = fmaxf(d * a5 + b1.y, 0.f);
      float o6 = fmaxf(d * a6 + b1.z, 0.f), o7 = fmaxf(d * a7 + b1.w, 0.f);
      uint4 pk;
      pk.x = (unsigned)f2bf(o0) | ((unsigned)f2bf(o1) << 16);
      pk.y = (unsigned)f2bf(o2) | ((unsigned)f2bf(o3) << 16);
      pk.z = (unsigned)f2bf(o4) | ((unsigned)f2bf(o5) << 16);
      pk.w = (unsigned)f2bf(o6) | ((unsigned)f2bf(o7) << 16);
      *(uint4*)&hs[vloc][c * 8] = pk;
    }
  }
  __syncthreads();

  // ---- Phase B: gemm on the 64x128 LDS h-tile -> gout = dinv * (h @ W) ----
  const int mt = wid & 3;
  const int nb = (wid >> 2) * 4;
  const int lr = lane & 15;
  const int lk = (lane >> 4) * 8;

  f32x4 acc[4];
#pragma unroll
  for (int j = 0; j < 4; ++j) acc[j] = (f32x4){0.f, 0.f, 0.f, 0.f};

#pragma unroll
  for (int ks = 0; ks < 4; ++ks) {
    const int k0 = ks * 32 + lk;
    bf16x8 a = *(const bf16x8*)&hs[mt * 16 + lr][k0];
#pragma unroll
    for (int j = 0; j < 4; ++j) {
      bf16x8 b = *(const bf16x8*)(Wt + (size_t)((nb + j) * 16 + lr) * HID + k0);
      acc[j] = __builtin_amdgcn_mfma_f32_16x16x32_bf16(a, b, acc[j], 0, 0, 0);
    }
  }

  const int drow = tile + mt * 16 + (lane >> 4) * 4;
#pragma unroll
  for (int j = 0; j < 4; ++j) {
    const int gcol = (nb + j) * 16 + lr;
#pragma unroll
    for (int r = 0; r < 4; ++r) {
      const int rr = drow + r;
      if (rr < N_NODES) gout[(size_t)rr * HID + gcol] = f2bf(acc[j][r] * dinv[rr]);
    }
  }
}

// ---------------- fused mean pool + heads ----------------
__global__ __launch_bounds__(1024) void k_poolheads(const unsigned short* __restrict__ h,
                                                    const int* __restrict__ gstart, const int* __restrict__ gend,
                                                    const float* __restrict__ W0, const float* __restrict__ b0,
                                                    const float* __restrict__ W1, const float* __restrict__ b1,
                                                    const float* __restrict__ W2, const float* __restrict__ b2,
                                                    float* __restrict__ out) {
  __shared__ float red[1024];
  __shared__ float pm[HID];
  const int g = blockIdx.x;
  const int tid = threadIdx.x;
  const int j = tid & 127;
  const int r0 = tid >> 7;
  const int lo = gstart[g], hi = gend[g];
  float acc = 0.f;
  for (int v = lo + r0; v < hi; v += 8) acc += bf2f(h[(size_t)v * HID + j]);
  red[tid] = acc;
  __syncthreads();
  if (r0 < 4) red[tid] += red[tid + 512];
  __syncthreads();
  if (r0 < 2) red[tid] += red[tid + 256];
  __syncthreads();
  if (r0 < 1) {
    float s = red[tid] + red[tid + 128];
    pm[j] = s / fmaxf((float)(hi - lo), 1.f);
  }
  __syncthreads();
  if (tid < 384) {
    const int t = tid >> 7;        // head 0..2
    const int cc = tid & 127;      // col
    const float* W = (t == 0) ? W0 : ((t == 1) ? W1 : W2);
    const float* b = (t == 0) ? b0 : ((t == 1) ? b1 : b2);
    float a2 = 0.f;
#pragma unroll 8
    for (int k = 0; k < HID; ++k) a2 += pm[k] * W[k * HID + cc];
    out[((size_t)t * NGRAPH + g) * HID + cc] = a2 + b[cc];
  }
}

extern "C" void kernel_launch(void* const* d_in, const int* in_sizes, int n_in,
                              void* d_out, int out_size, void* d_ws, size_t ws_size,
                              hipStream_t stream) {
  const float* x     = (const float*)d_in[0];
  const int*   ei    = (const int*)d_in[1];
  const int*   batch = (const int*)d_in[2];
  const float* W_in  = (const float*)d_in[3];
  const float* b_in  = (const float*)d_in[4];
  const float* convW = (const float*)d_in[5];
  const float* convb = (const float*)d_in[6];
  const float* W_def = (const float*)d_in[7];
  const float* b_def = (const float*)d_in[8];
  const float* W_syn = (const float*)d_in[9];
  const float* b_syn = (const float*)d_in[10];
  const float* W_rel = (const float*)d_in[11];
  const float* b_rel = (const float*)d_in[12];

  const int E = in_sizes[1] / 2;  // 640000
  const int* row = ei;            // source
  const int* col = ei + E;        // target

  char* base = (char*)d_ws;
  size_t off = 0;
  auto alloc = [&](size_t bytes) -> void* {
    void* p = base + off;
    off += (bytes + 255) & ~size_t(255);
    return p;
  };
  int*   cnt     = (int*)  alloc((size_t)N_NODES * 4);
  float* dinv    = (float*)alloc((size_t)N_NODES * 4);
  int*   offs    = (int*)  alloc((size_t)(N_NODES + 1) * 4);
  int*   cursor  = (int*)  alloc((size_t)N_NODES * 4);
  int*   excl    = (int*)  alloc((size_t)N_NODES * 4);
  int*   bsum    = (int*)  alloc((size_t)SCAN_NB * 4);
  unsigned short* csr_src = (unsigned short*)alloc((size_t)E * 2);
  unsigned short* hA = (unsigned short*)alloc((size_t)N_NODES * HID * 2);  // bf16 h4
  unsigned short* hB = (unsigned short*)alloc((size_t)N_NODES * HID * 2);  // bf16 g (ping)
  unsigned short* hC = (unsigned short*)alloc((size_t)N_NODES * HID * 2);  // bf16 g (pong)
  unsigned short* WtAll = (unsigned short*)alloc((size_t)5 * HID * HID * 2);
  int*   gstart  = (int*)  alloc((size_t)NGRAPH * 4);
  int*   gend    = (int*)  alloc((size_t)NGRAPH * 4);

  // graph preprocessing
  k_init<<<(N_NODES + 255) / 256, 256, 0, stream>>>(cnt, gstart, gend);
  k_hist<<<HIST_NB + WPREP_NB, 256, 0, stream>>>(col, E, cnt, batch, gstart, gend, W_in, convW, WtAll);
  k_scan1<<<SCAN_NB, 512, 0, stream>>>(cnt, excl, bsum);
  k_scan2<<<1, 128, 0, stream>>>(bsum, offs);
  k_scan3<<<SCAN_NB, 512, 0, stream>>>(cnt, excl, bsum, offs, cursor, dinv);

  // merged: CSR fill (scatter-bound) || fused prologue gemm01 (MFMA-bound)
  k_fillgemm<<<GEMM_NB + FILL_NB, 512, 0, stream>>>(row, col, E, cursor, csr_src,
                                                    x, WtAll, b_in, WtAll + (size_t)1 * HID * HID,
                                                    dinv, hB);

  // layers 0..2: fused agg(g_i) -> h_{i+1} (LDS only) -> g_{i+1} = dinv*(h @ convW[i+1])
  unsigned short* gin = hB;
  unsigned short* gout = hC;
  for (int i = 0; i < 3; ++i) {
    k_agggemm<<<GEMM_NB, 512, 0, stream>>>(gin, offs, csr_src, dinv,
                                           convb + (size_t)i * HID,
                                           WtAll + (size_t)(i + 2) * HID * HID, gout);
    unsigned short* t = gin; gin = gout; gout = t;
  }

  // last layer: h4 = relu(dinv*agg(g3) + convb[3])  (row-major for pooling)
  k_agg<<<(N_NODES + 3) / 4, 256, 0, stream>>>(gin, offs, csr_src, dinv,
                                               convb + (size_t)3 * HID, hA);

  k_poolheads<<<NGRAPH, 1024, 0, stream>>>(hA, gstart, gend, W_def, b_def, W_syn, b_syn, W_rel, b_rel,
                                           (float*)d_out);
}

// Round 19
// 295.195 us; speedup vs baseline: 1.2680x; 1.0051x over previous
//
#include <hip/hip_runtime.h>
#include <hip/hip_bf16.h>

#define N_NODES 50000
#define NGRAPH 64
#define HID 128
#define NLAYERS 4
#define SCAN_NB ((N_NODES + 511) / 512)   // 98 blocks
#define HIST_NB 2500                      // ceil(640000/256)
#define WPREP_NB 320                      // ceil(5*128*128/256)
#define GEMM_NB ((N_NODES + 63) / 64)     // 782
#define FILL_NB 1250                      // ceil(640000/512)
#define ATILE 32
#define AGG_GRID ((N_NODES + ATILE - 1) / ATILE)  // 1563

typedef __attribute__((ext_vector_type(8))) __bf16 bf16x8;
typedef __attribute__((ext_vector_type(8))) unsigned short ushort8;
typedef __attribute__((ext_vector_type(4))) float f32x4;

__device__ __forceinline__ float bf2f(unsigned short u) { return __uint_as_float(((unsigned)u) << 16); }
__device__ __forceinline__ unsigned short f2bf(float f) { return __hip_bfloat16_raw(__float2bfloat16(f)).x; }
__device__ __forceinline__ float ulo(unsigned m) { return __uint_as_float(m << 16); }
__device__ __forceinline__ float uhi(unsigned m) { return __uint_as_float(m & 0xffff0000u); }

// ---------------- init: zero histogram + graph bounds ----------------
__global__ void k_init(int* __restrict__ cnt, int* __restrict__ gstart, int* __restrict__ gend) {
  int i = blockIdx.x * blockDim.x + threadIdx.x;
  if (i < N_NODES) cnt[i] = 0;
  if (i < NGRAPH) { gstart[i] = 0; gend[i] = 0; }
}

// ---------------- fused: histogram over target + graph bounds + weight prep ----------------
__global__ void k_hist(const int* __restrict__ col, int E, int* __restrict__ cnt,
                       const int* __restrict__ batch, int* __restrict__ gstart, int* __restrict__ gend,
                       const float* __restrict__ Win, const float* __restrict__ Wconv,
                       unsigned short* __restrict__ WtAll) {
  if (blockIdx.x < HIST_NB) {
    int e = blockIdx.x * blockDim.x + threadIdx.x;
    if (e < E) atomicAdd(&cnt[col[e]], 1);
    if (e < N_NODES) {
      int b = batch[e];
      if (e == 0 || batch[e - 1] != b) gstart[b] = e;
      if (e == N_NODES - 1 || batch[e + 1] != b) gend[b] = e + 1;
    }
  } else {
    int idx = (blockIdx.x - HIST_NB) * 256 + threadIdx.x;
    if (idx >= 5 * HID * HID) return;
    int m = idx >> 14, rem = idx & 16383;
    int k = rem >> 7, n = rem & 127;
    const float* src = (m == 0) ? Win : (Wconv + (size_t)(m - 1) * HID * HID);
    WtAll[(size_t)m * HID * HID + n * HID + k] = f2bf(src[k * HID + n]);
  }
}

// ---------------- multi-block scan ----------------
__global__ __launch_bounds__(512) void k_scan1(const int* __restrict__ cnt, int* __restrict__ excl,
                                               int* __restrict__ bsum) {
  __shared__ int tmp[512];
  const int t = threadIdx.x;
  const int i = blockIdx.x * 512 + t;
  int v = (i < N_NODES) ? cnt[i] : 0;
  tmp[t] = v;
  __syncthreads();
#pragma unroll
  for (int off = 1; off < 512; off <<= 1) {
    int u = (t >= off) ? tmp[t - off] : 0;
    __syncthreads();
    tmp[t] += u;
    __syncthreads();
  }
  if (i < N_NODES) excl[i] = tmp[t] - v;
  if (t == 511) bsum[blockIdx.x] = tmp[511];
}

__global__ __launch_bounds__(128) void k_scan2(int* __restrict__ bsum, int* __restrict__ offs) {
  __shared__ int tmp[128];
  const int t = threadIdx.x;
  int v = (t < SCAN_NB) ? bsum[t] : 0;
  tmp[t] = v;
  __syncthreads();
#pragma unroll
  for (int off = 1; off < 128; off <<= 1) {
    int u = (t >= off) ? tmp[t - off] : 0;
    __syncthreads();
    tmp[t] += u;
    __syncthreads();
  }
  if (t < SCAN_NB) bsum[t] = tmp[t] - v;
  if (t == 127) offs[N_NODES] = tmp[127];
}

__global__ __launch_bounds__(512) void k_scan3(const int* __restrict__ cnt, const int* __restrict__ excl,
                                               const int* __restrict__ bsum, int* __restrict__ offs,
                                               int* __restrict__ cursor, float* __restrict__ dinv) {
  const int i = blockIdx.x * 512 + threadIdx.x;
  if (i >= N_NODES) return;
  int o = excl[i] + bsum[blockIdx.x];
  offs[i] = o;
  cursor[i] = o;
  dinv[i] = 1.0f / sqrtf((float)(cnt[i] + 1));
}

// ---------------- MERGED: gemm01 (blocks 0..GEMM_NB) || CSR fill (blocks GEMM_NB..) ----------------
__global__ __launch_bounds__(512) void k_fillgemm(const int* __restrict__ row, const int* __restrict__ col,
                                                  int E, int* __restrict__ cursor,
                                                  unsigned short* __restrict__ csr_src,
                                                  const float* __restrict__ x,
                                                  const unsigned short* __restrict__ Wt0,
                                                  const float* __restrict__ b_in,
                                                  const unsigned short* __restrict__ Wt1,
                                                  const float* __restrict__ dinv,
                                                  unsigned short* __restrict__ gout) {
  __shared__ unsigned short hs[64][136];
  if (blockIdx.x >= GEMM_NB) {
    // ---- fill body ----
    int e = (blockIdx.x - GEMM_NB) * 512 + threadIdx.x;
    if (e < E) {
      int pos = atomicAdd(&cursor[col[e]], 1);
      csr_src[pos] = (unsigned short)row[e];
    }
    return;
  }

  // ---- gemm01 body ----
  const int wid = threadIdx.x >> 6;
  const int lane = threadIdx.x & 63;
  const int tile = blockIdx.x * 64;
  const int lr = lane & 15;
  const int lk = (lane >> 4) * 8;
  const int mt = wid & 3;
  const int nb = (wid >> 2) * 4;

  f32x4 acc[4];
#pragma unroll
  for (int j = 0; j < 4; ++j) acc[j] = (f32x4){0.f, 0.f, 0.f, 0.f};

  const int arow = min(tile + mt * 16 + lr, N_NODES - 1);
#pragma unroll
  for (int ks = 0; ks < 4; ++ks) {
    const int k0 = ks * 32 + lk;
    float4 f0 = *(const float4*)(x + (size_t)arow * HID + k0);
    float4 f1 = *(const float4*)(x + (size_t)arow * HID + k0 + 4);
    ushort8 u;
    u[0] = f2bf(f0.x); u[1] = f2bf(f0.y); u[2] = f2bf(f0.z); u[3] = f2bf(f0.w);
    u[4] = f2bf(f1.x); u[5] = f2bf(f1.y); u[6] = f2bf(f1.z); u[7] = f2bf(f1.w);
    bf16x8 a = __builtin_bit_cast(bf16x8, u);
#pragma unroll
    for (int j = 0; j < 4; ++j) {
      bf16x8 b = *(const bf16x8*)(Wt0 + (size_t)((nb + j) * 16 + lr) * HID + k0);
      acc[j] = __builtin_amdgcn_mfma_f32_16x16x32_bf16(a, b, acc[j], 0, 0, 0);
    }
  }
  const int drloc = mt * 16 + (lane >> 4) * 4;
#pragma unroll
  for (int j = 0; j < 4; ++j) {
    const int gcol = (nb + j) * 16 + lr;
    const float bv = b_in[gcol];
#pragma unroll
    for (int r = 0; r < 4; ++r)
      hs[drloc + r][gcol] = f2bf(fmaxf(acc[j][r] + bv, 0.f));
  }
  __syncthreads();

#pragma unroll
  for (int j = 0; j < 4; ++j) acc[j] = (f32x4){0.f, 0.f, 0.f, 0.f};

#pragma unroll
  for (int ks = 0; ks < 4; ++ks) {
    const int k0 = ks * 32 + lk;
    bf16x8 a = *(const bf16x8*)&hs[mt * 16 + lr][k0];
#pragma unroll
    for (int j = 0; j < 4; ++j) {
      bf16x8 b = *(const bf16x8*)(Wt1 + (size_t)((nb + j) * 16 + lr) * HID + k0);
      acc[j] = __builtin_amdgcn_mfma_f32_16x16x32_bf16(a, b, acc[j], 0, 0, 0);
    }
  }
  const int drow = tile + mt * 16 + (lane >> 4) * 4;
#pragma unroll
  for (int j = 0; j < 4; ++j) {
    const int gcol = (nb + j) * 16 + lr;
#pragma unroll
    for (int r = 0; r < 4; ++r) {
      const int rr = drow + r;
      if (rr < N_NODES) gout[(size_t)rr * HID + gcol] = f2bf(acc[j][r] * dinv[rr]);
    }
  }
}

// ---------------- aggregation: wave/node, 4 edge-slots x 16 lanes x uint4 (16B) ----------------
__global__ __launch_bounds__(256) void k_agg(const unsigned short* __restrict__ g, const int* __restrict__ offs,
                                             const unsigned short* __restrict__ csr_src,
                                             const float* __restrict__ dinv,
                                             const float* __restrict__ bias, unsigned short* __restrict__ out) {
  const int wave = threadIdx.x >> 6;
  const int lane = threadIdx.x & 63;
  const int v = blockIdx.x * 4 + wave;
  if (v >= N_NODES) return;
  const int s = lane >> 4;          // edge slot 0..3
  const int c = lane & 15;          // 16B chunk within 256B row

  const uint4* g4 = (const uint4*)g;   // row = 16 x uint4

  float a0 = 0.f, a1 = 0.f, a2 = 0.f, a3 = 0.f, a4 = 0.f, a5 = 0.f, a6 = 0.f, a7 = 0.f;
  if (s == 0) {                        // self term in slot 0
    uint4 m = g4[(size_t)v * 16 + c];
    a0 = ulo(m.x); a1 = uhi(m.x); a2 = ulo(m.y); a3 = uhi(m.y);
    a4 = ulo(m.z); a5 = uhi(m.z); a6 = ulo(m.w); a7 = uhi(m.w);
  }

  const int lo = offs[v], hi = offs[v + 1];
  int idx = lo + s;
  for (; idx + 4 < hi; idx += 8) {
    int s0 = csr_src[idx];
    int s1 = csr_src[idx + 4];
    uint4 m0 = g4[(size_t)s0 * 16 + c];
    uint4 m1 = g4[(size_t)s1 * 16 + c];
    a0 += ulo(m0.x) + ulo(m1.x); a1 += uhi(m0.x) + uhi(m1.x);
    a2 += ulo(m0.y) + ulo(m1.y); a3 += uhi(m0.y) + uhi(m1.y);
    a4 += ulo(m0.z) + ulo(m1.z); a5 += uhi(m0.z) + uhi(m1.z);
    a6 += ulo(m0.w) + ulo(m1.w); a7 += uhi(m0.w) + uhi(m1.w);
  }
  if (idx < hi) {
    uint4 m0 = g4[(size_t)csr_src[idx] * 16 + c];
    a0 += ulo(m0.x); a1 += uhi(m0.x);
    a2 += ulo(m0.y); a3 += uhi(m0.y);
    a4 += ulo(m0.z); a5 += uhi(m0.z);
    a6 += ulo(m0.w); a7 += uhi(m0.w);
  }

  a0 += __shfl_xor(a0, 16, 64); a0 += __shfl_xor(a0, 32, 64);
  a1 += __shfl_xor(a1, 16, 64); a1 += __shfl_xor(a1, 32, 64);
  a2 += __shfl_xor(a2, 16, 64); a2 += __shfl_xor(a2, 32, 64);
  a3 += __shfl_xor(a3, 16, 64); a3 += __shfl_xor(a3, 32, 64);
  a4 += __shfl_xor(a4, 16, 64); a4 += __shfl_xor(a4, 32, 64);
  a5 += __shfl_xor(a5, 16, 64); a5 += __shfl_xor(a5, 32, 64);
  a6 += __shfl_xor(a6, 16, 64); a6 += __shfl_xor(a6, 32, 64);
  a7 += __shfl_xor(a7, 16, 64); a7 += __shfl_xor(a7, 32, 64);

  if (s == 0) {
    const float d = dinv[v];
    float4 b0 = ((const float4*)bias)[c * 2];
    float4 b1 = ((const float4*)bias)[c * 2 + 1];
    float o0 = fmaxf(d * a0 + b0.x, 0.f), o1 = fmaxf(d * a1 + b0.y, 0.f);
    float o2 = fmaxf(d * a2 + b0.z, 0.f), o3 = fmaxf(d * a3 + b0.w, 0.f);
    float o4 = fmaxf(d * a4 + b1.x, 0.f), o5 = fmaxf(d * a5 + b1.y, 0.f);
    float o6 = fmaxf(d * a6 + b1.z, 0.f), o7 = fmaxf(d * a7 + b1.w, 0.f);
    uint4 pk;
    pk.x = (unsigned)f2bf(o0) | ((unsigned)f2bf(o1) << 16);
    pk.y = (unsigned)f2bf(o2) | ((unsigned)f2bf(o3) << 16);
    pk.z = (unsigned)f2bf(o4) | ((unsigned)f2bf(o5) << 16);
    pk.w = (unsigned)f2bf(o6) | ((unsigned)f2bf(o7) << 16);
    ((uint4*)out)[(size_t)v * 16 + c] = pk;
  }
}

// ---------------- FUSED agg + next-layer gemm (32-node tiles for full occupancy) ----------------
// Grid = 1563 blocks of 512 threads -> ~6 blocks/CU available, 4 resident = 32 waves/CU.
// Phase A: each wave aggregates 4 nodes (R15 body verbatim). Phase B: 32-row LDS gemm,
// wave -> (mt = wid&1, N-tiles (wid>>1)*2 .. +1).
__global__ __launch_bounds__(512) void k_agggemm(const unsigned short* __restrict__ g,
                                                 const int* __restrict__ offs,
                                                 const unsigned short* __restrict__ csr_src,
                                                 const float* __restrict__ dinv,
                                                 const float* __restrict__ bias,
                                                 const unsigned short* __restrict__ Wt,
                                                 unsigned short* __restrict__ gout) {
  __shared__ unsigned short hs[ATILE][136];  // 8.7 KB
  const int wid = threadIdx.x >> 6;
  const int lane = threadIdx.x & 63;
  const int s = lane >> 4;
  const int c = lane & 15;
  const int tile = blockIdx.x * ATILE;
  const uint4* g4 = (const uint4*)g;

  // ---- Phase A: aggregate 4 nodes per wave ----
  for (int it = 0; it < 4; ++it) {
    const int vloc = wid * 4 + it;
    const int v = tile + vloc;
    if (v >= N_NODES) break;

    float a0 = 0.f, a1 = 0.f, a2 = 0.f, a3 = 0.f, a4 = 0.f, a5 = 0.f, a6 = 0.f, a7 = 0.f;
    if (s == 0) {
      uint4 m = g4[(size_t)v * 16 + c];
      a0 = ulo(m.x); a1 = uhi(m.x); a2 = ulo(m.y); a3 = uhi(m.y);
      a4 = ulo(m.z); a5 = uhi(m.z); a6 = ulo(m.w); a7 = uhi(m.w);
    }
    const int lo = offs[v], hi = offs[v + 1];
    int idx = lo + s;
    for (; idx + 4 < hi; idx += 8) {
      int s0 = csr_src[idx];
      int s1 = csr_src[idx + 4];
      uint4 m0 = g4[(size_t)s0 * 16 + c];
      uint4 m1 = g4[(size_t)s1 * 16 + c];
      a0 += ulo(m0.x) + ulo(m1.x); a1 += uhi(m0.x) + uhi(m1.x);
      a2 += ulo(m0.y) + ulo(m1.y); a3 += uhi(m0.y) + uhi(m1.y);
      a4 += ulo(m0.z) + ulo(m1.z); a5 += uhi(m0.z) + uhi(m1.z);
      a6 += ulo(m0.w) + ulo(m1.w); a7 += uhi(m0.w) + uhi(m1.w);
    }
    if (idx < hi) {
      uint4 m0 = g4[(size_t)csr_src[idx] * 16 + c];
      a0 += ulo(m0.x); a1 += uhi(m0.x);
      a2 += ulo(m0.y); a3 += uhi(m0.y);
      a4 += ulo(m0.z); a5 += uhi(m0.z);
      a6 += ulo(m0.w); a7 += uhi(m0.w);
    }
    a0 += __shfl_xor(a0, 16, 64); a0 += __shfl_xor(a0, 32, 64);
    a1 += __shfl_xor(a1, 16, 64); a1 += __shfl_xor(a1, 32, 64);
    a2 += __shfl_xor(a2, 16, 64); a2 += __shfl_xor(a2, 32, 64);
    a3 += __shfl_xor(a3, 16, 64); a3 += __shfl_xor(a3, 32, 64);
    a4 += __shfl_xor(a4, 16, 64); a4 += __shfl_xor(a4, 32, 64);
    a5 += __shfl_xor(a5, 16, 64); a5 += __shfl_xor(a5, 32, 64);
    a6 += __shfl_xor(a6, 16, 64); a6 += __shfl_xor(a6, 32, 64);
    a7 += __shfl_xor(a7, 16, 64); a7 += __shfl_xor(a7, 32, 64);

    if (s == 0) {
      const float d = dinv[v];
      float4 b0 = ((const float4*)bias)[c * 2];
      float4 b1 = ((const float4*)bias)[c * 2 + 1];
      float o0 = fmaxf(d * a0 + b0.x, 0.f), o1 = fmaxf(d * a1 + b0.y, 0.f);
      float o2 = fmaxf(d * a2 + b0.z, 0.f), o3 = fmaxf(d * a3 + b0.w, 0.f);
      float o4 = fmaxf(d * a4 + b1.x, 0.f), o5 = fmaxf(d * a5 + b1.y, 0.f);
      float o6 = fmaxf(d * a6 + b1.z, 0.f), o7 = fmaxf(d * a7 + b1.w, 0.f);
      uint4 pk;
      pk.x = (unsigned)f2bf(o0) | ((unsigned)f2bf(o1) << 16);
      pk.y = (unsigned)f2bf(o2) | ((unsigned)f2bf(o3) << 16);
      pk.z = (unsigned)f2bf(o4) | ((unsigned)f2bf(o5) << 16);
      pk.w = (unsigned)f2bf(o6) | ((unsigned)f2bf(o7) << 16);
      *(uint4*)&hs[vloc][c * 8] = pk;
    }
  }
  __syncthreads();

  // ---- Phase B: gemm on the 32x128 LDS h-tile -> gout = dinv * (h @ W) ----
  const int mt = wid & 1;          // M-tile 0..1
  const int nbase = (wid >> 1) * 2; // N-tiles nbase..nbase+1
  const int lr = lane & 15;
  const int lk = (lane >> 4) * 8;

  f32x4 acc[2];
#pragma unroll
  for (int j = 0; j < 2; ++j) acc[j] = (f32x4){0.f, 0.f, 0.f, 0.f};

#pragma unroll
  for (int ks = 0; ks < 4; ++ks) {
    const int k0 = ks * 32 + lk;
    bf16x8 a = *(const bf16x8*)&hs[mt * 16 + lr][k0];
#pragma unroll
    for (int j = 0; j < 2; ++j) {
      bf16x8 b = *(const bf16x8*)(Wt + (size_t)((nbase + j) * 16 + lr) * HID + k0);
      acc[j] = __builtin_amdgcn_mfma_f32_16x16x32_bf16(a, b, acc[j], 0, 0, 0);
    }
  }

  const int drow = tile + mt * 16 + (lane >> 4) * 4;
#pragma unroll
  for (int j = 0; j < 2; ++j) {
    const int gcol = (nbase + j) * 16 + lr;
#pragma unroll
    for (int r = 0; r < 4; ++r) {
      const int rr = drow + r;
      if (rr < N_NODES) gout[(size_t)rr * HID + gcol] = f2bf(acc[j][r] * dinv[rr]);
    }
  }
}

// ---------------- fused mean pool + heads ----------------
__global__ __launch_bounds__(1024) void k_poolheads(const unsigned short* __restrict__ h,
                                                    const int* __restrict__ gstart, const int* __restrict__ gend,
                                                    const float* __restrict__ W0, const float* __restrict__ b0,
                                                    const float* __restrict__ W1, const float* __restrict__ b1,
                                                    const float* __restrict__ W2, const float* __restrict__ b2,
                                                    float* __restrict__ out) {
  __shared__ float red[1024];
  __shared__ float pm[HID];
  const int g = blockIdx.x;
  const int tid = threadIdx.x;
  const int j = tid & 127;
  const int r0 = tid >> 7;
  const int lo = gstart[g], hi = gend[g];
  float acc = 0.f;
  for (int v = lo + r0; v < hi; v += 8) acc += bf2f(h[(size_t)v * HID + j]);
  red[tid] = acc;
  __syncthreads();
  if (r0 < 4) red[tid] += red[tid + 512];
  __syncthreads();
  if (r0 < 2) red[tid] += red[tid + 256];
  __syncthreads();
  if (r0 < 1) {
    float s = red[tid] + red[tid + 128];
    pm[j] = s / fmaxf((float)(hi - lo), 1.f);
  }
  __syncthreads();
  if (tid < 384) {
    const int t = tid >> 7;        // head 0..2
    const int cc = tid & 127;      // col
    const float* W = (t == 0) ? W0 : ((t == 1) ? W1 : W2);
    const float* b = (t == 0) ? b0 : ((t == 1) ? b1 : b2);
    float a2 = 0.f;
#pragma unroll 8
    for (int k = 0; k < HID; ++k) a2 += pm[k] * W[k * HID + cc];
    out[((size_t)t * NGRAPH + g) * HID + cc] = a2 + b[cc];
  }
}

extern "C" void kernel_launch(void* const* d_in, const int* in_sizes, int n_in,
                              void* d_out, int out_size, void* d_ws, size_t ws_size,
                              hipStream_t stream) {
  const float* x     = (const float*)d_in[0];
  const int*   ei    = (const int*)d_in[1];
  const int*   batch = (const int*)d_in[2];
  const float* W_in  = (const float*)d_in[3];
  const float* b_in  = (const float*)d_in[4];
  const float* convW = (const float*)d_in[5];
  const float* convb = (const float*)d_in[6];
  const float* W_def = (const float*)d_in[7];
  const float* b_def = (const float*)d_in[8];
  const float* W_syn = (const float*)d_in[9];
  const float* b_syn = (const float*)d_in[10];
  const float* W_rel = (const float*)d_in[11];
  const float* b_rel = (const float*)d_in[12];

  const int E = in_sizes[1] / 2;  // 640000
  const int* row = ei;            // source
  const int* col = ei + E;        // target

  char* base = (char*)d_ws;
  size_t off = 0;
  auto alloc = [&](size_t bytes) -> void* {
    void* p = base + off;
    off += (bytes + 255) & ~size_t(255);
    return p;
  };
  int*   cnt     = (int*)  alloc((size_t)N_NODES * 4);
  float* dinv    = (float*)alloc((size_t)N_NODES * 4);
  int*   offs    = (int*)  alloc((size_t)(N_NODES + 1) * 4);
  int*   cursor  = (int*)  alloc((size_t)N_NODES * 4);
  int*   excl    = (int*)  alloc((size_t)N_NODES * 4);
  int*   bsum    = (int*)  alloc((size_t)SCAN_NB * 4);
  unsigned short* csr_src = (unsigned short*)alloc((size_t)E * 2);
  unsigned short* hA = (unsigned short*)alloc((size_t)N_NODES * HID * 2);  // bf16 h4
  unsigned short* hB = (unsigned short*)alloc((size_t)N_NODES * HID * 2);  // bf16 g (ping)
  unsigned short* hC = (unsigned short*)alloc((size_t)N_NODES * HID * 2);  // bf16 g (pong)
  unsigned short* WtAll = (unsigned short*)alloc((size_t)5 * HID * HID * 2);
  int*   gstart  = (int*)  alloc((size_t)NGRAPH * 4);
  int*   gend    = (int*)  alloc((size_t)NGRAPH * 4);

  // graph preprocessing
  k_init<<<(N_NODES + 255) / 256, 256, 0, stream>>>(cnt, gstart, gend);
  k_hist<<<HIST_NB + WPREP_NB, 256, 0, stream>>>(col, E, cnt, batch, gstart, gend, W_in, convW, WtAll);
  k_scan1<<<SCAN_NB, 512, 0, stream>>>(cnt, excl, bsum);
  k_scan2<<<1, 128, 0, stream>>>(bsum, offs);
  k_scan3<<<SCAN_NB, 512, 0, stream>>>(cnt, excl, bsum, offs, cursor, dinv);

  // merged: CSR fill (scatter-bound) || fused prologue gemm01 (MFMA-bound)
  k_fillgemm<<<GEMM_NB + FILL_NB, 512, 0, stream>>>(row, col, E, cursor, csr_src,
                                                    x, WtAll, b_in, WtAll + (size_t)1 * HID * HID,
                                                    dinv, hB);

  // layers 0..2: fused agg(g_i) -> h_{i+1} (LDS only) -> g_{i+1} = dinv*(h @ convW[i+1])
  unsigned short* gin = hB;
  unsigned short* gout = hC;
  for (int i = 0; i < 3; ++i) {
    k_agggemm<<<AGG_GRID, 512, 0, stream>>>(gin, offs, csr_src, dinv,
                                            convb + (size_t)i * HID,
                                            WtAll + (size_t)(i + 2) * HID * HID, gout);
    unsigned short* t = gin; gin = gout; gout = t;
  }

  // last layer: h4 = relu(dinv*agg(g3) + convb[3])  (row-major for pooling)
  k_agg<<<(N_NODES + 3) / 4, 256, 0, stream>>>(gin, offs, csr_src, dinv,
                                               convb + (size_t)3 * HID, hA);

  k_poolheads<<<NGRAPH, 1024, 0, stream>>>(hA, gstart, gend, W_def, b_def, W_syn, b_syn, W_rel, b_rel,
                                           (float*)d_out);
}